// Round 4
// baseline (295.918 us; speedup 1.0000x reference)
//
#include <hip/hip_runtime.h>

#define D_MODEL 1024
#define NHEADS  16
#define DEPTH   64
#define BATCH   2
#define SEQ     2048
#define MROWS   (BATCH * SEQ)   // 4096
// 0.125 (1/sqrt(DEPTH)) * log2(e): folded into Q projection; flash uses raw v_exp_f32 (exp2)
#define QSCALE  0.18033688011112042f

typedef unsigned short u16;
typedef unsigned int   u32;
typedef unsigned long long u64;
typedef __bf16 bf16x8 __attribute__((ext_vector_type(8)));
typedef float  f32x4  __attribute__((ext_vector_type(4)));

#if __has_builtin(__builtin_amdgcn_exp2f)
#define EXP2(x) __builtin_amdgcn_exp2f(x)
#else
#define EXP2(x) exp2f(x)
#endif

__device__ __forceinline__ u16 f2b(float f) {
    return __builtin_bit_cast(u16, static_cast<__bf16>(f));   // v_cvt RNE
}
__device__ __forceinline__ bf16x8 ldb8(const u16* p) {
    return __builtin_bit_cast(bf16x8, *(const uint4*)p);
}
// async global->LDS, 16B per lane; LDS dest is wave-uniform base + lane*16
__device__ __forceinline__ void gload16(const u16* g, u16* l) {
    __builtin_amdgcn_global_load_lds(
        (const __attribute__((address_space(1))) void*)g,
        (__attribute__((address_space(3))) void*)l, 16, 0, 0);
}

// ---------------------------------------------------------------------------
// Pack mask f32 [B,S,S] (1 => masked) into bit-words: word (b*S+q)*32 + k64.
// ---------------------------------------------------------------------------
__global__ __launch_bounds__(256) void pack_mask(
    const float* __restrict__ mask, u64* __restrict__ bits)
{
    const int w    = blockIdx.x * 4 + (threadIdx.x >> 6);
    const int lane = threadIdx.x & 63;
    float m = mask[(size_t)w * 64 + lane];
    u64 b = __ballot(m > 0.5f);
    if (lane == 0) bits[w] = b;
}

// ---------------------------------------------------------------------------
// fp32 -> bf16 conversion: q,k,v (3 x 4M elems) then wq,wk,wv,wo (4 x 1M).
// ---------------------------------------------------------------------------
__global__ __launch_bounds__(256) void cvt_bf16(
    const float* __restrict__ q, const float* __restrict__ k, const float* __restrict__ v,
    const float* __restrict__ wq, const float* __restrict__ wk, const float* __restrict__ wv,
    const float* __restrict__ wo,
    u16* __restrict__ xb, u16* __restrict__ wb)
{
    const size_t e = ((size_t)blockIdx.x * 256 + threadIdx.x) * 8;
    const float* src;
    u16* dst;
    size_t off;
    if (e < 12582912) {                      // 3 * 4M: q,k,v
        const int a = (int)(e >> 22);
        off = e & 4194303;
        src = (a == 0) ? q : (a == 1) ? k : v;
        dst = xb + ((size_t)a << 22) + off;
    } else {                                 // 4 * 1M: wq,wk,wv,wo
        const size_t e2 = e - 12582912;
        const int a = (int)(e2 >> 20);
        off = e2 & 1048575;
        src = (a == 0) ? wq : (a == 1) ? wk : (a == 2) ? wv : wo;
        dst = wb + ((size_t)a << 20) + off;
    }
    const float4 f0 = *(const float4*)(src + off);
    const float4 f1 = *(const float4*)(src + off + 4);
    uint4 o;
    o.x = (u32)f2b(f0.x) | ((u32)f2b(f0.y) << 16);
    o.y = (u32)f2b(f0.z) | ((u32)f2b(f0.w) << 16);
    o.z = (u32)f2b(f1.x) | ((u32)f2b(f1.y) << 16);
    o.w = (u32)f2b(f1.z) | ((u32)f2b(f1.w) << 16);
    *(uint4*)dst = o;
}

// ---------------------------------------------------------------------------
// Merged Q/K/V projection, pure-bf16 inputs, m97 structure.
// Grid (8,32,3) = 768 blocks = 3/CU exactly. LDS 32 KB.
// ---------------------------------------------------------------------------
__global__ __launch_bounds__(256, 3) void proj3_bf16(
    const u16* __restrict__ xb, const u16* __restrict__ wb,
    const float* __restrict__ bq, const float* __restrict__ bk, const float* __restrict__ bv,
    u16* __restrict__ qws, u16* __restrict__ kws, u16* __restrict__ vtws)
{
    __shared__ __align__(16) u16 la[2][128 * 32];
    __shared__ __align__(16) u16 lb[2][128 * 32];

    const int z = blockIdx.z;
    const u16* X = xb + ((size_t)z << 22);
    const u16* W = wb + ((size_t)z << 20);
    const float* Bi = (z == 0) ? bq : (z == 1) ? bk : bv;
    u16* dst       = (z == 0) ? qws : (z == 1) ? kws : vtws;

    const int tid  = threadIdx.x;
    const int wv_  = tid >> 6;
    const int lane = tid & 63;
    const int quad = lane >> 4;
    const int l15  = lane & 15;
    const int bx = blockIdx.y >> 2;                            // 0..7
    const int by = (blockIdx.x << 2) | (blockIdx.y & 3);       // 0..31
    const int wm = (wv_ >> 1) * 64;
    const int wn = (wv_ & 1) * 64;

    f32x4 acc[4][4];
    for (int i = 0; i < 4; ++i)
        for (int j = 0; j < 4; ++j)
            acc[i][j] = (f32x4){0.f, 0.f, 0.f, 0.f};

    const int rowA0 = by * 128;
    const int rowB0 = bx * 128;

    const int strow = tid >> 2;
    const int stcol = (tid & 3) * 8;
    const u16* gA0 = &X[(size_t)(rowA0 + strow) * D_MODEL + stcol];
    const u16* gA1 = gA0 + (size_t)64 * D_MODEL;
    const u16* gB0 = &W[(size_t)(rowB0 + strow) * D_MODEL + stcol];
    const u16* gB1 = gB0 + (size_t)64 * D_MODEL;
    const int l0 = tid * 8, l1 = 2048 + tid * 8;

    gload16(gA0, &la[0][l0]);
    gload16(gA1, &la[0][l1]);
    gload16(gB0, &lb[0][l0]);
    gload16(gB1, &lb[0][l1]);
    __syncthreads();

    for (int t = 0; t < 32; ++t) {
        const int buf = t & 1;
        if (t < 31) {
            const int ko = (t + 1) * 32;
            gload16(gA0 + ko, &la[buf ^ 1][l0]);
            gload16(gA1 + ko, &la[buf ^ 1][l1]);
            gload16(gB0 + ko, &lb[buf ^ 1][l0]);
            gload16(gB1 + ko, &lb[buf ^ 1][l1]);
        }
        bf16x8 af[4], bfr[4];
        #pragma unroll
        for (int tt = 0; tt < 4; ++tt) {
            af[tt]  = ldb8(&la[buf][(wm + tt * 16 + l15) * 32 + quad * 8]);
            bfr[tt] = ldb8(&lb[buf][(wn + tt * 16 + l15) * 32 + quad * 8]);
        }
        #pragma unroll
        for (int mt = 0; mt < 4; ++mt)
            #pragma unroll
            for (int nt = 0; nt < 4; ++nt)
                acc[mt][nt] = __builtin_amdgcn_mfma_f32_16x16x32_bf16(af[mt], bfr[nt], acc[mt][nt], 0, 0, 0);
        __syncthreads();
    }

    #pragma unroll
    for (int nt = 0; nt < 4; ++nt) {
        int n = bx * 128 + wn + nt * 16 + l15;
        float bvv = Bi[n];
        int h = n >> 6, d = n & 63;
        #pragma unroll
        for (int mt = 0; mt < 4; ++mt) {
            #pragma unroll
            for (int r = 0; r < 4; ++r) {
                int m = by * 128 + wm + mt * 16 + quad * 4 + r;
                float c = acc[mt][nt][r] + bvv;
                if (z == 0) c *= QSCALE;
                int b = m >> 11, s = m & (SEQ - 1);
                if (z != 2)
                    dst[(((size_t)(b * NHEADS + h) * SEQ) + s) * DEPTH + d] = f2b(c);
                else
                    dst[(((size_t)(b * NHEADS + h) * DEPTH) + d) * SEQ + s] = f2b(c);
            }
        }
    }
}

// ---------------------------------------------------------------------------
// Fallback fused projection (fp32 in-kernel cvt) for small workspaces.
// ---------------------------------------------------------------------------
__global__ __launch_bounds__(256, 3) void proj3_fused(
    const float* __restrict__ q, const float* __restrict__ k, const float* __restrict__ v,
    const float* __restrict__ wq, const float* __restrict__ wk, const float* __restrict__ wv,
    const float* __restrict__ bq, const float* __restrict__ bk, const float* __restrict__ bv,
    u16* __restrict__ qws, u16* __restrict__ kws, u16* __restrict__ vtws)
{
    __shared__ __align__(16) u16 ldsA[128 * 40];
    __shared__ __align__(16) u16 ldsB[128 * 40];

    const int z = blockIdx.z;
    const float* X  = (z == 0) ? q  : (z == 1) ? k  : v;
    const float* W  = (z == 0) ? wq : (z == 1) ? wk : wv;
    const float* Bi = (z == 0) ? bq : (z == 1) ? bk : bv;
    u16* dst        = (z == 0) ? qws : (z == 1) ? kws : vtws;

    const int tid  = threadIdx.x;
    const int wv_  = tid >> 6;
    const int lane = tid & 63;
    const int quad = lane >> 4;
    const int l15  = lane & 15;
    const int bx = blockIdx.y >> 2;
    const int by = (blockIdx.x << 2) | (blockIdx.y & 3);
    const int wm = (wv_ >> 1) * 64;
    const int wn = (wv_ & 1) * 64;

    f32x4 acc[4][4];
    for (int i = 0; i < 4; ++i)
        for (int j = 0; j < 4; ++j)
            acc[i][j] = (f32x4){0.f, 0.f, 0.f, 0.f};

    const int rowA0 = by * 128;
    const int rowB0 = bx * 128;

    const int sr = tid >> 3;
    const int sc = (tid & 7) * 4;

    float4 pa[4], pb[4];
    #pragma unroll
    for (int i = 0; i < 4; ++i) {
        pa[i] = *(const float4*)&X[(size_t)(rowA0 + sr + i * 32) * D_MODEL + sc];
        pb[i] = *(const float4*)&W[(size_t)(rowB0 + sr + i * 32) * D_MODEL + sc];
    }

    for (int it = 0; it < 32; ++it) {
        #pragma unroll
        for (int i = 0; i < 4; ++i) {
            ushort4 ha, hb;
            ha.x = f2b(pa[i].x); ha.y = f2b(pa[i].y); ha.z = f2b(pa[i].z); ha.w = f2b(pa[i].w);
            hb.x = f2b(pb[i].x); hb.y = f2b(pb[i].y); hb.z = f2b(pb[i].z); hb.w = f2b(pb[i].w);
            *(ushort4*)&ldsA[(sr + i * 32) * 40 + sc] = ha;
            *(ushort4*)&ldsB[(sr + i * 32) * 40 + sc] = hb;
        }
        __syncthreads();

        if (it < 31) {
            const int k0 = (it + 1) * 32;
            #pragma unroll
            for (int i = 0; i < 4; ++i) {
                pa[i] = *(const float4*)&X[(size_t)(rowA0 + sr + i * 32) * D_MODEL + k0 + sc];
                pb[i] = *(const float4*)&W[(size_t)(rowB0 + sr + i * 32) * D_MODEL + k0 + sc];
            }
        }

        bf16x8 af[4], bfr[4];
        #pragma unroll
        for (int t = 0; t < 4; ++t) {
            af[t]  = ldb8(&ldsA[(wm + t * 16 + l15) * 40 + quad * 8]);
            bfr[t] = ldb8(&ldsB[(wn + t * 16 + l15) * 40 + quad * 8]);
        }
        #pragma unroll
        for (int mt = 0; mt < 4; ++mt)
            #pragma unroll
            for (int nt = 0; nt < 4; ++nt)
                acc[mt][nt] = __builtin_amdgcn_mfma_f32_16x16x32_bf16(af[mt], bfr[nt], acc[mt][nt], 0, 0, 0);
        __syncthreads();
    }

    #pragma unroll
    for (int nt = 0; nt < 4; ++nt) {
        int n = bx * 128 + wn + nt * 16 + l15;
        float bvv = Bi[n];
        int h = n >> 6, d = n & 63;
        #pragma unroll
        for (int mt = 0; mt < 4; ++mt) {
            #pragma unroll
            for (int r = 0; r < 4; ++r) {
                int m = by * 128 + wm + mt * 16 + quad * 4 + r;
                float c = acc[mt][nt][r] + bvv;
                if (z == 0) c *= QSCALE;
                int b = m >> 11, s = m & (SEQ - 1);
                if (z != 2)
                    dst[(((size_t)(b * NHEADS + h) * SEQ) + s) * DEPTH + d] = f2b(c);
                else
                    dst[(((size_t)(b * NHEADS + h) * DEPTH) + d) * SEQ + s] = f2b(c);
            }
        }
    }
}

// ---------------------------------------------------------------------------
// Output projection, pure-bf16 inputs, m97 structure. Grid (16,32) = 2/CU.
// ---------------------------------------------------------------------------
__global__ __launch_bounds__(256, 2) void gemm_out_bf16(
    const u16* __restrict__ X, const u16* __restrict__ W,
    const float* __restrict__ bias, float* __restrict__ out)
{
    __shared__ __align__(16) u16 la[2][128 * 32];
    __shared__ __align__(16) u16 lb[2][64 * 32];

    const int tid  = threadIdx.x;
    const int wv_  = tid >> 6;
    const int lane = tid & 63;
    const int quad = lane >> 4;
    const int l15  = lane & 15;
    const int bx = ((blockIdx.y >> 2) << 1) | (blockIdx.x >> 3);   // 0..15
    const int by = ((blockIdx.x & 7) << 2) | (blockIdx.y & 3);     // 0..31
    const int wm = (wv_ >> 1) * 64;
    const int wn = (wv_ & 1) * 32;

    f32x4 acc[4][2];
    for (int i = 0; i < 4; ++i)
        for (int j = 0; j < 2; ++j)
            acc[i][j] = (f32x4){0.f, 0.f, 0.f, 0.f};

    const int rowA0 = by * 128;
    const int rowB0 = bx * 64;

    const int strow = tid >> 2;
    const int stcol = (tid & 3) * 8;
    const u16* gA0 = &X[(size_t)(rowA0 + strow) * D_MODEL + stcol];
    const u16* gA1 = gA0 + (size_t)64 * D_MODEL;
    const u16* gB0 = &W[(size_t)(rowB0 + strow) * D_MODEL + stcol];
    const int l0 = tid * 8, l1 = 2048 + tid * 8;

    gload16(gA0, &la[0][l0]);
    gload16(gA1, &la[0][l1]);
    gload16(gB0, &lb[0][l0]);
    __syncthreads();

    for (int t = 0; t < 32; ++t) {
        const int buf = t & 1;
        if (t < 31) {
            const int ko = (t + 1) * 32;
            gload16(gA0 + ko, &la[buf ^ 1][l0]);
            gload16(gA1 + ko, &la[buf ^ 1][l1]);
            gload16(gB0 + ko, &lb[buf ^ 1][l0]);
        }
        bf16x8 af[4], bfr[2];
        #pragma unroll
        for (int tt = 0; tt < 4; ++tt)
            af[tt] = ldb8(&la[buf][(wm + tt * 16 + l15) * 32 + quad * 8]);
        #pragma unroll
        for (int tt = 0; tt < 2; ++tt)
            bfr[tt] = ldb8(&lb[buf][(wn + tt * 16 + l15) * 32 + quad * 8]);
        #pragma unroll
        for (int mt = 0; mt < 4; ++mt)
            #pragma unroll
            for (int nt = 0; nt < 2; ++nt)
                acc[mt][nt] = __builtin_amdgcn_mfma_f32_16x16x32_bf16(af[mt], bfr[nt], acc[mt][nt], 0, 0, 0);
        __syncthreads();
    }

    #pragma unroll
    for (int nt = 0; nt < 2; ++nt) {
        int n = bx * 64 + wn + nt * 16 + l15;
        float bvv = bias[n];
        #pragma unroll
        for (int mt = 0; mt < 4; ++mt) {
            #pragma unroll
            for (int r = 0; r < 4; ++r) {
                int m = by * 128 + wm + mt * 16 + quad * 4 + r;
                out[(size_t)m * D_MODEL + n] = acc[mt][nt][r] + bvv;
            }
        }
    }
}

// ---------------------------------------------------------------------------
// Fallback output projection (fp32 W, reg-staged).
// ---------------------------------------------------------------------------
__global__ __launch_bounds__(256) void gemm_out_f32(
    const u16* __restrict__ X, const float* __restrict__ W,
    const float* __restrict__ bias, float* __restrict__ out)
{
    __shared__ __align__(16) u16 ldsA[128 * 40];
    __shared__ __align__(16) u16 ldsB[64 * 40];

    const int tid  = threadIdx.x;
    const int wv_  = tid >> 6;
    const int lane = tid & 63;
    const int quad = lane >> 4;
    const int l15  = lane & 15;
    const int bx = ((blockIdx.y >> 2) << 1) | (blockIdx.x >> 3);   // 0..15
    const int by = ((blockIdx.x & 7) << 2) | (blockIdx.y & 3);     // 0..31
    const int wm = (wv_ >> 1) * 64;
    const int wn = (wv_ & 1) * 32;

    f32x4 acc[4][2];
    for (int i = 0; i < 4; ++i)
        for (int j = 0; j < 2; ++j)
            acc[i][j] = (f32x4){0.f, 0.f, 0.f, 0.f};

    const int rowA0 = by * 128;
    const int rowB0 = bx * 64;

    const int ar = tid >> 2, akc = (tid & 3) * 8;
    const int br = tid >> 3, bc = (tid & 7) * 4;

    uint4  paA[2];
    float4 paB[2];
    #pragma unroll
    for (int i = 0; i < 2; ++i) {
        paA[i] = *(const uint4*)&X[(size_t)(rowA0 + ar + i * 64) * D_MODEL + akc];
        paB[i] = *(const float4*)&W[(size_t)(rowB0 + br + i * 32) * D_MODEL + bc];
    }

    for (int it = 0; it < 32; ++it) {
        #pragma unroll
        for (int i = 0; i < 2; ++i) {
            *(uint4*)&ldsA[(ar + i * 64) * 40 + akc] = paA[i];
            ushort4 hb;
            hb.x = f2b(paB[i].x); hb.y = f2b(paB[i].y); hb.z = f2b(paB[i].z); hb.w = f2b(paB[i].w);
            *(ushort4*)&ldsB[(br + i * 32) * 40 + bc] = hb;
        }
        __syncthreads();

        if (it < 31) {
            const int k0 = (it + 1) * 32;
            #pragma unroll
            for (int i = 0; i < 2; ++i) {
                paA[i] = *(const uint4*)&X[(size_t)(rowA0 + ar + i * 64) * D_MODEL + k0 + akc];
                paB[i] = *(const float4*)&W[(size_t)(rowB0 + br + i * 32) * D_MODEL + k0 + bc];
            }
        }

        bf16x8 af[4], bfr[2];
        #pragma unroll
        for (int t = 0; t < 4; ++t)
            af[t] = ldb8(&ldsA[(wm + t * 16 + l15) * 40 + quad * 8]);
        #pragma unroll
        for (int t = 0; t < 2; ++t)
            bfr[t] = ldb8(&ldsB[(wn + t * 16 + l15) * 40 + quad * 8]);
        #pragma unroll
        for (int mt = 0; mt < 4; ++mt)
            #pragma unroll
            for (int nt = 0; nt < 2; ++nt)
                acc[mt][nt] = __builtin_amdgcn_mfma_f32_16x16x32_bf16(af[mt], bfr[nt], acc[mt][nt], 0, 0, 0);
        __syncthreads();
    }

    #pragma unroll
    for (int nt = 0; nt < 2; ++nt) {
        int n = bx * 64 + wn + nt * 16 + l15;
        float bvv = bias[n];
        #pragma unroll
        for (int mt = 0; mt < 4; ++mt) {
            #pragma unroll
            for (int r = 0; r < 4; ++r) {
                int m = by * 128 + wm + mt * 16 + quad * 4 + r;
                out[(size_t)m * D_MODEL + n] = acc[mt][nt][r] + bvv;
            }
        }
    }
}

// ---------------------------------------------------------------------------
// Flash attention, KV-SPLIT by 2. QBLK=32/wave, block = 128 q-rows x 1024 kv.
// Grid (32,32) = 1024 blocks = 4/CU exact (LDS 32 KB, single-buffered K/V,
// launch_bounds(256,4) => 16 waves/CU — restores the TLP round-2 lost).
// Softmax is max-free (raw exp2) so partials are additive: each block writes
// unnormalized O (f32) and row-sum l; combine_o normalizes.
// XCD swizzle: same bh => same (x&7) => same XCD; the two kv-halves of one
// (bh,qt) sit at x and x+8 => same XCD => shared Q/partials L2-local.
// ---------------------------------------------------------------------------
__global__ __launch_bounds__(256, 4) void flash_attn_split(
    const u16* __restrict__ Q, const u16* __restrict__ K,
    const u16* __restrict__ Vt, const u64* __restrict__ maskbits,
    float* __restrict__ Opart, float* __restrict__ lpart)
{
    __shared__ __align__(16) u16 ldsK[64 * 64];
    __shared__ __align__(16) u16 ldsV[64 * 64];
    __shared__ __align__(16) u16 ldsP[4][32 * 64];

    const int tid  = threadIdx.x;
    const int wv_  = tid >> 6;
    const int lane = tid & 63;
    const int quad = lane >> 4;
    const int l15  = lane & 15;
    const int bh  = ((blockIdx.x & 7) << 2) | (blockIdx.y & 3);     // 0..31
    const int qt5 = ((blockIdx.y >> 2) << 2) | (blockIdx.x >> 3);   // 0..31
    const int qt  = qt5 >> 1;                                       // 0..15
    const int kvh = qt5 & 1;
    const int b  = bh >> 4;
    const int q0 = qt * 128 + wv_ * 32;
    const int c0 = kvh * (SEQ / 2);

    const u16* Qb = Q  + (size_t)bh * SEQ * DEPTH;
    const u16* Kb = K  + (size_t)bh * SEQ * DEPTH;
    const u16* Vb = Vt + (size_t)bh * DEPTH * SEQ;
    const u64* MB = maskbits + (size_t)b * SEQ * (SEQ / 64);

    const int srow = tid >> 3;
    const int sc8  = tid & 7;
    const int swz  = ((sc8 ^ (srow & 7)) * 8);
    const int kdst0 = srow * 64 + swz;
    const int kdst1 = (srow + 32) * 64 + swz;

    const int xk0 = ((quad ^ (l15 & 7)) * 8);
    const int xk1 = (((4 + quad) ^ (l15 & 7)) * 8);

    bf16x8 aq0[2], aq1[2];
    #pragma unroll
    for (int f = 0; f < 2; ++f) {
        aq0[f] = ldb8(&Qb[(q0 + f * 16 + l15) * DEPTH + quad * 8]);
        aq1[f] = ldb8(&Qb[(q0 + f * 16 + l15) * DEPTH + 32 + quad * 8]);
    }

    bf16x8 vones;
    #pragma unroll
    for (int i = 0; i < 8; ++i) vones[i] = (__bf16)1.0f;

    f32x4 oa[2][4];
    #pragma unroll
    for (int f = 0; f < 2; ++f)
        for (int i = 0; i < 4; ++i) oa[f][i] = (f32x4){0.f, 0.f, 0.f, 0.f};
    f32x4 lacc[2];
    lacc[0] = (f32x4){0.f, 0.f, 0.f, 0.f};
    lacc[1] = (f32x4){0.f, 0.f, 0.f, 0.f};

    u16* myP = ldsP[wv_];

    int wpa[4][4];
    #pragma unroll
    for (int cc = 0; cc < 4; ++cc)
        #pragma unroll
        for (int r = 0; r < 4; ++r) {
            const int row  = quad * 4 + r;
            const int colg = cc * 2 + (l15 >> 3);
            wpa[cc][r] = row * 64 + ((colg ^ (row & 7)) * 8) + (l15 & 7);
        }
    int rp0_[2], rp1_[2];
    #pragma unroll
    for (int f = 0; f < 2; ++f) {
        rp0_[f] = (f * 16 + l15) * 64 + ((quad ^ (l15 & 7)) * 8);
        rp1_[f] = (f * 16 + l15) * 64 + (((4 + quad) ^ (l15 & 7)) * 8);
    }

    uint4 kreg0 = *(const uint4*)&Kb[(size_t)(c0 + srow) * DEPTH + sc8 * 8];
    uint4 kreg1 = *(const uint4*)&Kb[(size_t)(c0 + srow + 32) * DEPTH + sc8 * 8];
    uint4 vreg0 = *(const uint4*)&Vb[(size_t)srow * SEQ + c0 + sc8 * 8];
    uint4 vreg1 = *(const uint4*)&Vb[(size_t)(srow + 32) * SEQ + c0 + sc8 * 8];

    for (int it = 0; it < 16; ++it) {
        __syncthreads();   // previous iter's LDS reads complete before overwrite
        *(uint4*)&ldsK[kdst0] = kreg0;
        *(uint4*)&ldsK[kdst1] = kreg1;
        *(uint4*)&ldsV[kdst0] = vreg0;
        *(uint4*)&ldsV[kdst1] = vreg1;
        __syncthreads();

        if (it < 15) {
            const int cn = c0 + (it + 1) * 64;
            kreg0 = *(const uint4*)&Kb[(size_t)(cn + srow) * DEPTH + sc8 * 8];
            kreg1 = *(const uint4*)&Kb[(size_t)(cn + srow + 32) * DEPTH + sc8 * 8];
            vreg0 = *(const uint4*)&Vb[(size_t)srow * SEQ + cn + sc8 * 8];
            vreg1 = *(const uint4*)&Vb[(size_t)(srow + 32) * SEQ + cn + sc8 * 8];
        }

        const int itg = kvh * 16 + it;
        u32 tlo[2][4], thi[2][4];
        #pragma unroll
        for (int f = 0; f < 2; ++f)
            #pragma unroll
            for (int r = 0; r < 4; ++r) {
                u64 t = MB[(size_t)(q0 + f * 16 + quad * 4 + r) * (SEQ / 64) + itg] >> l15;
                tlo[f][r] = (u32)t;
                thi[f][r] = (u32)(t >> 32);
            }

        #pragma unroll
        for (int cc = 0; cc < 4; ++cc) {
            const int row = cc * 16 + l15;
            bf16x8 bk0 = ldb8(&ldsK[row * 64 + xk0]);
            bf16x8 bk1 = ldb8(&ldsK[row * 64 + xk1]);
            #pragma unroll
            for (int f = 0; f < 2; ++f) {
                f32x4 z = (f32x4){0.f, 0.f, 0.f, 0.f};
                z = __builtin_amdgcn_mfma_f32_16x16x32_bf16(aq0[f], bk0, z, 0, 0, 0);
                z = __builtin_amdgcn_mfma_f32_16x16x32_bf16(aq1[f], bk1, z, 0, 0, 0);
                #pragma unroll
                for (int r = 0; r < 4; ++r) {
                    u32 w   = (cc < 2) ? tlo[f][r] : thi[f][r];
                    u32 bit = (cc & 1) ? ((w >> 16) & 1u) : (w & 1u);
                    float e = EXP2(z[r]);        // Q pre-scaled by 0.125*log2(e)
                    float p = bit ? 0.f : e;
                    myP[wpa[cc][r] + f * 1024] = f2b(p);
                }
            }
        }

        __builtin_amdgcn_wave_barrier();
        __builtin_amdgcn_s_waitcnt(0xc07f);   // lgkmcnt(0)
        __builtin_amdgcn_wave_barrier();
        bf16x8 pa0[2], pa1[2];
        #pragma unroll
        for (int f = 0; f < 2; ++f) {
            pa0[f] = ldb8(&myP[rp0_[f]]);
            pa1[f] = ldb8(&myP[rp1_[f]]);
        }

        #pragma unroll
        for (int f = 0; f < 2; ++f) {
            lacc[f] = __builtin_amdgcn_mfma_f32_16x16x32_bf16(pa0[f], vones, lacc[f], 0, 0, 0);
            lacc[f] = __builtin_amdgcn_mfma_f32_16x16x32_bf16(pa1[f], vones, lacc[f], 0, 0, 0);
        }

        #pragma unroll
        for (int n = 0; n < 4; ++n) {
            const int row = n * 16 + l15;
            bf16x8 bv0 = ldb8(&ldsV[row * 64 + xk0]);
            bf16x8 bv1 = ldb8(&ldsV[row * 64 + xk1]);
            #pragma unroll
            for (int f = 0; f < 2; ++f) {
                oa[f][n] = __builtin_amdgcn_mfma_f32_16x16x32_bf16(pa0[f], bv0, oa[f][n], 0, 0, 0);
                oa[f][n] = __builtin_amdgcn_mfma_f32_16x16x32_bf16(pa1[f], bv1, oa[f][n], 0, 0, 0);
            }
        }
    }

    // epilogue: unnormalized partials. lacc is uniform across the 16 cols
    // (ones-product => every col = row sum), so one lane per row writes l.
    if (l15 == 0) {
        #pragma unroll
        for (int f = 0; f < 2; ++f)
            #pragma unroll
            for (int r = 0; r < 4; ++r)
                lpart[(size_t)kvh * 65536 + (size_t)bh * SEQ + q0 + f * 16 + quad * 4 + r] = lacc[f][r];
    }
    #pragma unroll
    for (int f = 0; f < 2; ++f)
        #pragma unroll
        for (int n = 0; n < 4; ++n)
            #pragma unroll
            for (int r = 0; r < 4; ++r) {
                const int m = q0 + f * 16 + quad * 4 + r;
                Opart[(((size_t)kvh * 32 + bh) * SEQ + m) * DEPTH + n * 16 + l15] = oa[f][n][r];
            }
}

// ---------------------------------------------------------------------------
// Combine kv-half partials: O = (O0+O1)/(l0+l1), write bf16 ows row-major
// [B*S][D_MODEL]. Grid 2048 x 256, 8 elems/thread. ~40 MB traffic.
// ---------------------------------------------------------------------------
__global__ __launch_bounds__(256) void combine_o(
    const float* __restrict__ Op, const float* __restrict__ lp,
    u16* __restrict__ ows)
{
    const size_t idx = ((size_t)blockIdx.x * 256 + threadIdx.x) * 8;  // [32][2048][64]
    const int row = (int)(idx >> 6);          // bh*2048 + s
    const int d0  = (int)(idx & 63);
    const float* p0 = Op + (size_t)row * 64 + d0;
    const float4 a0 = *(const float4*)p0;
    const float4 a1 = *(const float4*)(p0 + 4);
    const float4 b0 = *(const float4*)(p0 + 4194304);
    const float4 b1 = *(const float4*)(p0 + 4194308);
    const float inv = 1.0f / (lp[row] + lp[65536 + row]);
    const int bh = row >> 11, s = row & 2047;
    const int b = bh >> 4, h = bh & 15;
    u16* o = ows + ((size_t)b * SEQ + s) * D_MODEL + h * DEPTH + d0;
    ushort4 w0, w1;
    w0.x = f2b((a0.x + b0.x) * inv);
    w0.y = f2b((a0.y + b0.y) * inv);
    w0.z = f2b((a0.z + b0.z) * inv);
    w0.w = f2b((a0.w + b0.w) * inv);
    w1.x = f2b((a1.x + b1.x) * inv);
    w1.y = f2b((a1.y + b1.y) * inv);
    w1.z = f2b((a1.z + b1.z) * inv);
    w1.w = f2b((a1.w + b1.w) * inv);
    *(ushort4*)o = w0;
    *(ushort4*)(o + 4) = w1;
}

// ---------------------------------------------------------------------------
// Fallback flash (round-2): QBLK=32, K/V dbuf, grid (32,16), direct output.
// ---------------------------------------------------------------------------
__global__ __launch_bounds__(256, 2) void flash_attn(
    const u16* __restrict__ Q, const u16* __restrict__ K,
    const u16* __restrict__ Vt, const u64* __restrict__ maskbits,
    u16* __restrict__ O)
{
    __shared__ __align__(16) u16 ldsK[2][64 * 64];
    __shared__ __align__(16) u16 ldsV[2][64 * 64];
    __shared__ __align__(16) u16 ldsP[4][32 * 64];

    const int tid  = threadIdx.x;
    const int wv_  = tid >> 6;
    const int lane = tid & 63;
    const int quad = lane >> 4;
    const int l15  = lane & 15;
    const int bh = ((blockIdx.x & 7) << 2) | (blockIdx.y & 3);     // 0..31
    const int qt = ((blockIdx.y >> 2) << 2) | (blockIdx.x >> 3);   // 0..15
    const int b  = bh >> 4, h = bh & 15;
    const int q0 = qt * 128 + wv_ * 32;

    const u16* Qb = Q  + (size_t)bh * SEQ * DEPTH;
    const u16* Kb = K  + (size_t)bh * SEQ * DEPTH;
    const u16* Vb = Vt + (size_t)bh * DEPTH * SEQ;
    const u64* MB = maskbits + (size_t)b * SEQ * (SEQ / 64);

    const int srow = tid >> 3;
    const int sc8  = tid & 7;
    const int swz  = ((sc8 ^ (srow & 7)) * 8);
    const int kdst0 = srow * 64 + swz;
    const int kdst1 = (srow + 32) * 64 + swz;

    const int xk0 = ((quad ^ (l15 & 7)) * 8);
    const int xk1 = (((4 + quad) ^ (l15 & 7)) * 8);

    bf16x8 aq0[2], aq1[2];
    #pragma unroll
    for (int f = 0; f < 2; ++f) {
        aq0[f] = ldb8(&Qb[(q0 + f * 16 + l15) * DEPTH + quad * 8]);
        aq1[f] = ldb8(&Qb[(q0 + f * 16 + l15) * DEPTH + 32 + quad * 8]);
    }

    bf16x8 vones;
    #pragma unroll
    for (int i = 0; i < 8; ++i) vones[i] = (__bf16)1.0f;

    f32x4 oa[2][4];
    #pragma unroll
    for (int f = 0; f < 2; ++f)
        for (int i = 0; i < 4; ++i) oa[f][i] = (f32x4){0.f, 0.f, 0.f, 0.f};
    f32x4 lacc[2];
    lacc[0] = (f32x4){0.f, 0.f, 0.f, 0.f};
    lacc[1] = (f32x4){0.f, 0.f, 0.f, 0.f};

    u16* myP = ldsP[wv_];

    int wpa[4][4];
    #pragma unroll
    for (int cc = 0; cc < 4; ++cc)
        #pragma unroll
        for (int r = 0; r < 4; ++r) {
            const int row  = quad * 4 + r;
            const int colg = cc * 2 + (l15 >> 3);
            wpa[cc][r] = row * 64 + ((colg ^ (row & 7)) * 8) + (l15 & 7);
        }
    int rp0_[2], rp1_[2];
    #pragma unroll
    for (int f = 0; f < 2; ++f) {
        rp0_[f] = (f * 16 + l15) * 64 + ((quad ^ (l15 & 7)) * 8);
        rp1_[f] = (f * 16 + l15) * 64 + (((4 + quad) ^ (l15 & 7)) * 8);
    }

    uint4 kreg0 = *(const uint4*)&Kb[(size_t)srow * DEPTH + sc8 * 8];
    uint4 kreg1 = *(const uint4*)&Kb[(size_t)(srow + 32) * DEPTH + sc8 * 8];
    uint4 vreg0 = *(const uint4*)&Vb[(size_t)srow * SEQ + sc8 * 8];
    uint4 vreg1 = *(const uint4*)&Vb[(size_t)(srow + 32) * SEQ + sc8 * 8];

    for (int it = 0; it < 32; ++it) {
        const int buf = it & 1;
        u16* Kl = ldsK[buf];
        u16* Vl = ldsV[buf];

        *(uint4*)&Kl[kdst0] = kreg0;
        *(uint4*)&Kl[kdst1] = kreg1;
        *(uint4*)&Vl[kdst0] = vreg0;
        *(uint4*)&Vl[kdst1] = vreg1;
        __syncthreads();

        if (it < 31) {
            const int kb2 = (it + 1) * 64;
            kreg0 = *(const uint4*)&Kb[(size_t)(kb2 + srow) * DEPTH + sc8 * 8];
            kreg1 = *(const uint4*)&Kb[(size_t)(kb2 + srow + 32) * DEPTH + sc8 * 8];
            vreg0 = *(const uint4*)&Vb[(size_t)srow * SEQ + kb2 + sc8 * 8];
            vreg1 = *(const uint4*)&Vb[(size_t)(srow + 32) * SEQ + kb2 + sc8 * 8];
        }

        u32 tlo[2][4], thi[2][4];
        #pragma unroll
        for (int f = 0; f < 2; ++f)
            #pragma unroll
            for (int r = 0; r < 4; ++r) {
                u64 t = MB[(size_t)(q0 + f * 16 + quad * 4 + r) * (SEQ / 64) + it] >> l15;
                tlo[f][r] = (u32)t;
                thi[f][r] = (u32)(t >> 32);
            }

        #pragma unroll
        for (int cc = 0; cc < 4; ++cc) {
            const int row = cc * 16 + l15;
            bf16x8 bk0 = ldb8(&Kl[row * 64 + xk0]);
            bf16x8 bk1 = ldb8(&Kl[row * 64 + xk1]);
            #pragma unroll
            for (int f = 0; f < 2; ++f) {
                f32x4 z = (f32x4){0.f, 0.f, 0.f, 0.f};
                z = __builtin_amdgcn_mfma_f32_16x16x32_bf16(aq0[f], bk0, z, 0, 0, 0);
                z = __builtin_amdgcn_mfma_f32_16x16x32_bf16(aq1[f], bk1, z, 0, 0, 0);
                #pragma unroll
                for (int r = 0; r < 4; ++r) {
                    u32 w   = (cc < 2) ? tlo[f][r] : thi[f][r];
                    u32 bit = (cc & 1) ? ((w >> 16) & 1u) : (w & 1u);
                    float e = EXP2(z[r]);
                    float p = bit ? 0.f : e;
                    myP[wpa[cc][r] + f * 1024] = f2b(p);
                }
            }
        }

        __builtin_amdgcn_wave_barrier();
        __builtin_amdgcn_s_waitcnt(0xc07f);   // lgkmcnt(0)
        __builtin_amdgcn_wave_barrier();
        bf16x8 pa0[2], pa1[2];
        #pragma unroll
        for (int f = 0; f < 2; ++f) {
            pa0[f] = ldb8(&myP[rp0_[f]]);
            pa1[f] = ldb8(&myP[rp1_[f]]);
        }

        #pragma unroll
        for (int f = 0; f < 2; ++f) {
            lacc[f] = __builtin_amdgcn_mfma_f32_16x16x32_bf16(pa0[f], vones, lacc[f], 0, 0, 0);
            lacc[f] = __builtin_amdgcn_mfma_f32_16x16x32_bf16(pa1[f], vones, lacc[f], 0, 0, 0);
        }

        #pragma unroll
        for (int n = 0; n < 4; ++n) {
            const int row = n * 16 + l15;
            bf16x8 bv0 = ldb8(&Vl[row * 64 + xk0]);
            bf16x8 bv1 = ldb8(&Vl[row * 64 + xk1]);
            #pragma unroll
            for (int f = 0; f < 2; ++f) {
                oa[f][n] = __builtin_amdgcn_mfma_f32_16x16x32_bf16(pa0[f], bv0, oa[f][n], 0, 0, 0);
                oa[f][n] = __builtin_amdgcn_mfma_f32_16x16x32_bf16(pa1[f], bv1, oa[f][n], 0, 0, 0);
            }
        }
    }

    #pragma unroll
    for (int f = 0; f < 2; ++f) {
        float inv[4];
        #pragma unroll
        for (int r = 0; r < 4; ++r)
            inv[r] = 1.0f / lacc[f][r];
        #pragma unroll
        for (int n = 0; n < 4; ++n)
            #pragma unroll
            for (int r = 0; r < 4; ++r) {
                int m = q0 + f * 16 + quad * 4 + r;
                O[((size_t)b * SEQ + m) * D_MODEL + h * DEPTH + n * 16 + l15] =
                    f2b(oa[f][n][r] * inv[r]);
            }
    }
}

// ---------------------------------------------------------------------------
extern "C" void kernel_launch(void* const* d_in, const int* in_sizes, int n_in,
                              void* d_out, int out_size, void* d_ws, size_t ws_size,
                              hipStream_t stream) {
    const float* q    = (const float*)d_in[0];
    const float* k    = (const float*)d_in[1];
    const float* v    = (const float*)d_in[2];
    const float* mask = (const float*)d_in[3];
    const float* wq   = (const float*)d_in[4];
    const float* bq   = (const float*)d_in[5];
    const float* wk   = (const float*)d_in[6];
    const float* bk   = (const float*)d_in[7];
    const float* wv   = (const float*)d_in[8];
    const float* bv   = (const float*)d_in[9];
    const float* wo   = (const float*)d_in[10];
    const float* bo   = (const float*)d_in[11];

    // ws (u16 units): [qws 4M][kws 4M][vtws 4M][ows 4M][mbits 512K][wb 4M][xb 12M]
    // split path overlays Opart (8.39M f32) + lpart (128K f32) on xb (dead
    // after proj3_bf16) and the tail beyond it.
    u16* base = (u16*)d_ws;
    const size_t seg = (size_t)BATCH * NHEADS * SEQ * DEPTH;  // 4M elems
    u16* qws  = base;
    u16* kws  = base + seg;
    u16* vtws = base + 2 * seg;
    u16* ows  = base + 3 * seg;
    u64* mbits = (u64*)(base + 4 * seg);
    u16* wb   = base + 4 * seg + 524288;
    u16* xb   = wb + 4 * 1048576;
    float* Opart = (float*)xb;
    float* lpart = Opart + 8388608;
    const size_t off_xb_u16 = 4 * seg + 524288 + 4 * 1048576;
    const size_t need_bf16  = (off_xb_u16 + 3 * seg) * 2;
    const size_t need_split = off_xb_u16 * 2 + (8388608u + 131072u) * 4;
    const bool bf16path  = (ws_size >= need_bf16);
    const bool splitpath = bf16path && (ws_size >= need_split);

    dim3 blk(256);
    hipLaunchKernelGGL(pack_mask, dim3(BATCH * SEQ * (SEQ / 64) / 4), blk, 0, stream, mask, mbits);

    dim3 gp(D_MODEL / 128, MROWS / 128, 3);   // (8, 32, 3)
    if (bf16path) {
        hipLaunchKernelGGL(cvt_bf16, dim3(8192), blk, 0, stream,
                           q, k, v, wq, wk, wv, wo, xb, wb);
        hipLaunchKernelGGL(proj3_bf16, gp, blk, 0, stream,
                           xb, wb, bq, bk, bv, qws, kws, vtws);
    } else {
        hipLaunchKernelGGL(proj3_fused, gp, blk, 0, stream,
                           q, k, v, wq, wk, wv, bq, bk, bv, qws, kws, vtws);
    }

    if (splitpath) {
        dim3 ga(32, 32);                      // 1024 blocks = 4/CU
        hipLaunchKernelGGL(flash_attn_split, ga, blk, 0, stream,
                           qws, kws, vtws, mbits, Opart, lpart);
        hipLaunchKernelGGL(combine_o, dim3(2048), blk, 0, stream, Opart, lpart, ows);
    } else {
        dim3 ga(32, 16);                      // 512 blocks
        hipLaunchKernelGGL(flash_attn, ga, blk, 0, stream, qws, kws, vtws, mbits, ows);
    }

    dim3 go(D_MODEL / 64, MROWS / 128);       // (16, 32)
    if (bf16path) {
        hipLaunchKernelGGL(gemm_out_bf16, go, blk, 0, stream, ows, wb + 3 * 1048576, bo, (float*)d_out);
    } else {
        hipLaunchKernelGGL(gemm_out_f32, go, blk, 0, stream, ows, wo, bo, (float*)d_out);
    }
}

// Round 5
// 272.364 us; speedup vs baseline: 1.0865x; 1.0865x over previous
//
#include <hip/hip_runtime.h>

#define D_MODEL 1024
#define NHEADS  16
#define DEPTH   64
#define BATCH   2
#define SEQ     2048
#define MROWS   (BATCH * SEQ)   // 4096
// 0.125 (1/sqrt(DEPTH)) * log2(e): folded into Q projection; flash uses raw v_exp_f32 (exp2)
#define QSCALE  0.18033688011112042f

typedef unsigned short u16;
typedef unsigned int   u32;
typedef unsigned long long u64;
typedef __bf16 bf16x8 __attribute__((ext_vector_type(8)));
typedef float  f32x4  __attribute__((ext_vector_type(4)));

#if __has_builtin(__builtin_amdgcn_exp2f)
#define EXP2(x) __builtin_amdgcn_exp2f(x)
#else
#define EXP2(x) exp2f(x)
#endif

__device__ __forceinline__ u16 f2b(float f) {
    return __builtin_bit_cast(u16, static_cast<__bf16>(f));   // v_cvt RNE
}
__device__ __forceinline__ bf16x8 ldb8(const u16* p) {
    return __builtin_bit_cast(bf16x8, *(const uint4*)p);
}
// async global->LDS, 16B per lane; LDS dest is wave-uniform base + lane*16
__device__ __forceinline__ void gload16(const u16* g, u16* l) {
    __builtin_amdgcn_global_load_lds(
        (const __attribute__((address_space(1))) void*)g,
        (__attribute__((address_space(3))) void*)l, 16, 0, 0);
}

// ---------------------------------------------------------------------------
// Pack mask f32 [B,S,S] (1 => masked) into bit-words: word (b*S+q)*32 + k64.
// ---------------------------------------------------------------------------
__global__ __launch_bounds__(256) void pack_mask(
    const float* __restrict__ mask, u64* __restrict__ bits)
{
    const int w    = blockIdx.x * 4 + (threadIdx.x >> 6);
    const int lane = threadIdx.x & 63;
    float m = mask[(size_t)w * 64 + lane];
    u64 b = __ballot(m > 0.5f);
    if (lane == 0) bits[w] = b;
}

// ---------------------------------------------------------------------------
// fp32 -> bf16 conversion: q,k,v (3 x 4M elems) then wq,wk,wv,wo (4 x 1M).
// ---------------------------------------------------------------------------
__global__ __launch_bounds__(256) void cvt_bf16(
    const float* __restrict__ q, const float* __restrict__ k, const float* __restrict__ v,
    const float* __restrict__ wq, const float* __restrict__ wk, const float* __restrict__ wv,
    const float* __restrict__ wo,
    u16* __restrict__ xb, u16* __restrict__ wb)
{
    const size_t e = ((size_t)blockIdx.x * 256 + threadIdx.x) * 8;
    const float* src;
    u16* dst;
    size_t off;
    if (e < 12582912) {                      // 3 * 4M: q,k,v
        const int a = (int)(e >> 22);
        off = e & 4194303;
        src = (a == 0) ? q : (a == 1) ? k : v;
        dst = xb + ((size_t)a << 22) + off;
    } else {                                 // 4 * 1M: wq,wk,wv,wo
        const size_t e2 = e - 12582912;
        const int a = (int)(e2 >> 20);
        off = e2 & 1048575;
        src = (a == 0) ? wq : (a == 1) ? wk : (a == 2) ? wv : wo;
        dst = wb + ((size_t)a << 20) + off;
    }
    const float4 f0 = *(const float4*)(src + off);
    const float4 f1 = *(const float4*)(src + off + 4);
    uint4 o;
    o.x = (u32)f2b(f0.x) | ((u32)f2b(f0.y) << 16);
    o.y = (u32)f2b(f0.z) | ((u32)f2b(f0.w) << 16);
    o.z = (u32)f2b(f1.x) | ((u32)f2b(f1.y) << 16);
    o.w = (u32)f2b(f1.z) | ((u32)f2b(f1.w) << 16);
    *(uint4*)dst = o;
}

// ---------------------------------------------------------------------------
// Merged Q/K/V projection, pure-bf16 inputs, m97 structure.
// Grid (8,32,3) = 768 blocks = 3/CU exactly. LDS 32 KB.
// z==2 epilogue: transpose the 128x128 output tile in LDS (reusing the
// staging buffer, XOR-swizzled) => coalesced dwordx4 V^T stores instead of
// the 2-byte / 4-KB-stride scatter (8x write amplification, 44 MB -> 27 MB).
// ---------------------------------------------------------------------------
__global__ __launch_bounds__(256, 3) void proj3_bf16(
    const u16* __restrict__ xb, const u16* __restrict__ wb,
    const float* __restrict__ bq, const float* __restrict__ bk, const float* __restrict__ bv,
    u16* __restrict__ qws, u16* __restrict__ kws, u16* __restrict__ vtws)
{
    __shared__ __align__(16) u16 smem[16384];   // 32 KB: la | lb, reused as 128x128 transpose buf
    u16 (*la)[4096] = reinterpret_cast<u16(*)[4096]>(smem);
    u16 (*lb)[4096] = reinterpret_cast<u16(*)[4096]>(smem + 8192);

    const int z = blockIdx.z;
    const u16* X = xb + ((size_t)z << 22);
    const u16* W = wb + ((size_t)z << 20);
    const float* Bi = (z == 0) ? bq : (z == 1) ? bk : bv;
    u16* dst       = (z == 0) ? qws : (z == 1) ? kws : vtws;

    const int tid  = threadIdx.x;
    const int wv_  = tid >> 6;
    const int lane = tid & 63;
    const int quad = lane >> 4;
    const int l15  = lane & 15;
    const int bx = blockIdx.y >> 2;                            // 0..7
    const int by = (blockIdx.x << 2) | (blockIdx.y & 3);       // 0..31
    const int wm = (wv_ >> 1) * 64;
    const int wn = (wv_ & 1) * 64;

    f32x4 acc[4][4];
    for (int i = 0; i < 4; ++i)
        for (int j = 0; j < 4; ++j)
            acc[i][j] = (f32x4){0.f, 0.f, 0.f, 0.f};

    const int rowA0 = by * 128;
    const int rowB0 = bx * 128;

    const int strow = tid >> 2;
    const int stcol = (tid & 3) * 8;
    const u16* gA0 = &X[(size_t)(rowA0 + strow) * D_MODEL + stcol];
    const u16* gA1 = gA0 + (size_t)64 * D_MODEL;
    const u16* gB0 = &W[(size_t)(rowB0 + strow) * D_MODEL + stcol];
    const u16* gB1 = gB0 + (size_t)64 * D_MODEL;
    const int l0 = tid * 8, l1 = 2048 + tid * 8;

    gload16(gA0, &la[0][l0]);
    gload16(gA1, &la[0][l1]);
    gload16(gB0, &lb[0][l0]);
    gload16(gB1, &lb[0][l1]);
    __syncthreads();

    for (int t = 0; t < 32; ++t) {
        const int buf = t & 1;
        if (t < 31) {
            const int ko = (t + 1) * 32;
            gload16(gA0 + ko, &la[buf ^ 1][l0]);
            gload16(gA1 + ko, &la[buf ^ 1][l1]);
            gload16(gB0 + ko, &lb[buf ^ 1][l0]);
            gload16(gB1 + ko, &lb[buf ^ 1][l1]);
        }
        bf16x8 af[4], bfr[4];
        #pragma unroll
        for (int tt = 0; tt < 4; ++tt) {
            af[tt]  = ldb8(&la[buf][(wm + tt * 16 + l15) * 32 + quad * 8]);
            bfr[tt] = ldb8(&lb[buf][(wn + tt * 16 + l15) * 32 + quad * 8]);
        }
        #pragma unroll
        for (int mt = 0; mt < 4; ++mt)
            #pragma unroll
            for (int nt = 0; nt < 4; ++nt)
                acc[mt][nt] = __builtin_amdgcn_mfma_f32_16x16x32_bf16(af[mt], bfr[nt], acc[mt][nt], 0, 0, 0);
        __syncthreads();
    }

    if (z != 2) {
        #pragma unroll
        for (int nt = 0; nt < 4; ++nt) {
            int n = rowB0 + wn + nt * 16 + l15;
            float bvv = Bi[n];
            int h = n >> 6, d = n & 63;
            #pragma unroll
            for (int mt = 0; mt < 4; ++mt) {
                #pragma unroll
                for (int r = 0; r < 4; ++r) {
                    int m = rowA0 + wm + mt * 16 + quad * 4 + r;
                    float c = acc[mt][nt][r] + bvv;
                    if (z == 0) c *= QSCALE;
                    int b = m >> 11, s = m & (SEQ - 1);
                    dst[(((size_t)(b * NHEADS + h) * SEQ) + s) * DEPTH + d] = f2b(c);
                }
            }
        }
    } else {
        // stage C^T (128 n x 128 m) into swizzled LDS, then coalesced stores.
        // element (nl, ml): group g = ml>>3; addr = nl*128 + ((g^(nl&15))<<3) + (ml&7)
        #pragma unroll
        for (int nt = 0; nt < 4; ++nt) {
            const int nl = wn + nt * 16 + l15;
            const float bvv = Bi[rowB0 + nl];
            #pragma unroll
            for (int mt = 0; mt < 4; ++mt) {
                #pragma unroll
                for (int r2 = 0; r2 < 4; r2 += 2) {
                    const int ml = wm + mt * 16 + quad * 4 + r2;   // even
                    u32 pk = (u32)f2b(acc[mt][nt][r2] + bvv)
                           | ((u32)f2b(acc[mt][nt][r2 + 1] + bvv) << 16);
                    const int g = ml >> 3;
                    *(u32*)&smem[nl * 128 + (((g ^ (nl & 15)) << 3) | (ml & 7))] = pk;
                }
            }
        }
        __syncthreads();
        const int nl  = tid >> 1;                 // local n row 0..127
        const int cc0 = (tid & 1) * 64;           // m half
        const int n   = rowB0 + nl;
        const int bb  = rowA0 >> 11;              // uniform per block
        u16* dbase = dst + (((size_t)(bb * NHEADS + (n >> 6)) * DEPTH) + (n & 63)) * SEQ
                   + (rowA0 & (SEQ - 1)) + cc0;
        #pragma unroll
        for (int j = 0; j < 8; ++j) {
            const int g = (tid & 1) * 8 + j;
            *(uint4*)&dbase[j * 8] =
                *(const uint4*)&smem[nl * 128 + ((g ^ (nl & 15)) << 3)];
        }
    }
}

// ---------------------------------------------------------------------------
// Fallback fused projection (fp32 in-kernel cvt) for small workspaces.
// ---------------------------------------------------------------------------
__global__ __launch_bounds__(256, 3) void proj3_fused(
    const float* __restrict__ q, const float* __restrict__ k, const float* __restrict__ v,
    const float* __restrict__ wq, const float* __restrict__ wk, const float* __restrict__ wv,
    const float* __restrict__ bq, const float* __restrict__ bk, const float* __restrict__ bv,
    u16* __restrict__ qws, u16* __restrict__ kws, u16* __restrict__ vtws)
{
    __shared__ __align__(16) u16 ldsA[128 * 40];
    __shared__ __align__(16) u16 ldsB[128 * 40];

    const int z = blockIdx.z;
    const float* X  = (z == 0) ? q  : (z == 1) ? k  : v;
    const float* W  = (z == 0) ? wq : (z == 1) ? wk : wv;
    const float* Bi = (z == 0) ? bq : (z == 1) ? bk : bv;
    u16* dst        = (z == 0) ? qws : (z == 1) ? kws : vtws;

    const int tid  = threadIdx.x;
    const int wv_  = tid >> 6;
    const int lane = tid & 63;
    const int quad = lane >> 4;
    const int l15  = lane & 15;
    const int bx = blockIdx.y >> 2;
    const int by = (blockIdx.x << 2) | (blockIdx.y & 3);
    const int wm = (wv_ >> 1) * 64;
    const int wn = (wv_ & 1) * 64;

    f32x4 acc[4][4];
    for (int i = 0; i < 4; ++i)
        for (int j = 0; j < 4; ++j)
            acc[i][j] = (f32x4){0.f, 0.f, 0.f, 0.f};

    const int rowA0 = by * 128;
    const int rowB0 = bx * 128;

    const int sr = tid >> 3;
    const int sc = (tid & 7) * 4;

    float4 pa[4], pb[4];
    #pragma unroll
    for (int i = 0; i < 4; ++i) {
        pa[i] = *(const float4*)&X[(size_t)(rowA0 + sr + i * 32) * D_MODEL + sc];
        pb[i] = *(const float4*)&W[(size_t)(rowB0 + sr + i * 32) * D_MODEL + sc];
    }

    for (int it = 0; it < 32; ++it) {
        #pragma unroll
        for (int i = 0; i < 4; ++i) {
            ushort4 ha, hb;
            ha.x = f2b(pa[i].x); ha.y = f2b(pa[i].y); ha.z = f2b(pa[i].z); ha.w = f2b(pa[i].w);
            hb.x = f2b(pb[i].x); hb.y = f2b(pb[i].y); hb.z = f2b(pb[i].z); hb.w = f2b(pb[i].w);
            *(ushort4*)&ldsA[(sr + i * 32) * 40 + sc] = ha;
            *(ushort4*)&ldsB[(sr + i * 32) * 40 + sc] = hb;
        }
        __syncthreads();

        if (it < 31) {
            const int k0 = (it + 1) * 32;
            #pragma unroll
            for (int i = 0; i < 4; ++i) {
                pa[i] = *(const float4*)&X[(size_t)(rowA0 + sr + i * 32) * D_MODEL + k0 + sc];
                pb[i] = *(const float4*)&W[(size_t)(rowB0 + sr + i * 32) * D_MODEL + k0 + sc];
            }
        }

        bf16x8 af[4], bfr[4];
        #pragma unroll
        for (int t = 0; t < 4; ++t) {
            af[t]  = ldb8(&ldsA[(wm + t * 16 + l15) * 40 + quad * 8]);
            bfr[t] = ldb8(&ldsB[(wn + t * 16 + l15) * 40 + quad * 8]);
        }
        #pragma unroll
        for (int mt = 0; mt < 4; ++mt)
            #pragma unroll
            for (int nt = 0; nt < 4; ++nt)
                acc[mt][nt] = __builtin_amdgcn_mfma_f32_16x16x32_bf16(af[mt], bfr[nt], acc[mt][nt], 0, 0, 0);
        __syncthreads();
    }

    #pragma unroll
    for (int nt = 0; nt < 4; ++nt) {
        int n = bx * 128 + wn + nt * 16 + l15;
        float bvv = Bi[n];
        int h = n >> 6, d = n & 63;
        #pragma unroll
        for (int mt = 0; mt < 4; ++mt) {
            #pragma unroll
            for (int r = 0; r < 4; ++r) {
                int m = by * 128 + wm + mt * 16 + quad * 4 + r;
                float c = acc[mt][nt][r] + bvv;
                if (z == 0) c *= QSCALE;
                int b = m >> 11, s = m & (SEQ - 1);
                if (z != 2)
                    dst[(((size_t)(b * NHEADS + h) * SEQ) + s) * DEPTH + d] = f2b(c);
                else
                    dst[(((size_t)(b * NHEADS + h) * DEPTH) + d) * SEQ + s] = f2b(c);
            }
        }
    }
}

// ---------------------------------------------------------------------------
// Output projection, pure-bf16 inputs, m97 structure. Grid (16,32) = 2/CU.
// ---------------------------------------------------------------------------
__global__ __launch_bounds__(256, 2) void gemm_out_bf16(
    const u16* __restrict__ X, const u16* __restrict__ W,
    const float* __restrict__ bias, float* __restrict__ out)
{
    __shared__ __align__(16) u16 la[2][128 * 32];
    __shared__ __align__(16) u16 lb[2][64 * 32];

    const int tid  = threadIdx.x;
    const int wv_  = tid >> 6;
    const int lane = tid & 63;
    const int quad = lane >> 4;
    const int l15  = lane & 15;
    const int bx = ((blockIdx.y >> 2) << 1) | (blockIdx.x >> 3);   // 0..15
    const int by = ((blockIdx.x & 7) << 2) | (blockIdx.y & 3);     // 0..31
    const int wm = (wv_ >> 1) * 64;
    const int wn = (wv_ & 1) * 32;

    f32x4 acc[4][2];
    for (int i = 0; i < 4; ++i)
        for (int j = 0; j < 2; ++j)
            acc[i][j] = (f32x4){0.f, 0.f, 0.f, 0.f};

    const int rowA0 = by * 128;
    const int rowB0 = bx * 64;

    const int strow = tid >> 2;
    const int stcol = (tid & 3) * 8;
    const u16* gA0 = &X[(size_t)(rowA0 + strow) * D_MODEL + stcol];
    const u16* gA1 = gA0 + (size_t)64 * D_MODEL;
    const u16* gB0 = &W[(size_t)(rowB0 + strow) * D_MODEL + stcol];
    const int l0 = tid * 8, l1 = 2048 + tid * 8;

    gload16(gA0, &la[0][l0]);
    gload16(gA1, &la[0][l1]);
    gload16(gB0, &lb[0][l0]);
    __syncthreads();

    for (int t = 0; t < 32; ++t) {
        const int buf = t & 1;
        if (t < 31) {
            const int ko = (t + 1) * 32;
            gload16(gA0 + ko, &la[buf ^ 1][l0]);
            gload16(gA1 + ko, &la[buf ^ 1][l1]);
            gload16(gB0 + ko, &lb[buf ^ 1][l0]);
        }
        bf16x8 af[4], bfr[2];
        #pragma unroll
        for (int tt = 0; tt < 4; ++tt)
            af[tt] = ldb8(&la[buf][(wm + tt * 16 + l15) * 32 + quad * 8]);
        #pragma unroll
        for (int tt = 0; tt < 2; ++tt)
            bfr[tt] = ldb8(&lb[buf][(wn + tt * 16 + l15) * 32 + quad * 8]);
        #pragma unroll
        for (int mt = 0; mt < 4; ++mt)
            #pragma unroll
            for (int nt = 0; nt < 2; ++nt)
                acc[mt][nt] = __builtin_amdgcn_mfma_f32_16x16x32_bf16(af[mt], bfr[nt], acc[mt][nt], 0, 0, 0);
        __syncthreads();
    }

    #pragma unroll
    for (int nt = 0; nt < 2; ++nt) {
        int n = bx * 64 + wn + nt * 16 + l15;
        float bvv = bias[n];
        #pragma unroll
        for (int mt = 0; mt < 4; ++mt) {
            #pragma unroll
            for (int r = 0; r < 4; ++r) {
                int m = by * 128 + wm + mt * 16 + quad * 4 + r;
                out[(size_t)m * D_MODEL + n] = acc[mt][nt][r] + bvv;
            }
        }
    }
}

// ---------------------------------------------------------------------------
// Fallback output projection (fp32 W, reg-staged).
// ---------------------------------------------------------------------------
__global__ __launch_bounds__(256) void gemm_out_f32(
    const u16* __restrict__ X, const float* __restrict__ W,
    const float* __restrict__ bias, float* __restrict__ out)
{
    __shared__ __align__(16) u16 ldsA[128 * 40];
    __shared__ __align__(16) u16 ldsB[64 * 40];

    const int tid  = threadIdx.x;
    const int wv_  = tid >> 6;
    const int lane = tid & 63;
    const int quad = lane >> 4;
    const int l15  = lane & 15;
    const int bx = ((blockIdx.y >> 2) << 1) | (blockIdx.x >> 3);   // 0..15
    const int by = ((blockIdx.x & 7) << 2) | (blockIdx.y & 3);     // 0..31
    const int wm = (wv_ >> 1) * 64;
    const int wn = (wv_ & 1) * 32;

    f32x4 acc[4][2];
    for (int i = 0; i < 4; ++i)
        for (int j = 0; j < 2; ++j)
            acc[i][j] = (f32x4){0.f, 0.f, 0.f, 0.f};

    const int rowA0 = by * 128;
    const int rowB0 = bx * 64;

    const int ar = tid >> 2, akc = (tid & 3) * 8;
    const int br = tid >> 3, bc = (tid & 7) * 4;

    uint4  paA[2];
    float4 paB[2];
    #pragma unroll
    for (int i = 0; i < 2; ++i) {
        paA[i] = *(const uint4*)&X[(size_t)(rowA0 + ar + i * 64) * D_MODEL + akc];
        paB[i] = *(const float4*)&W[(size_t)(rowB0 + br + i * 32) * D_MODEL + bc];
    }

    for (int it = 0; it < 32; ++it) {
        #pragma unroll
        for (int i = 0; i < 2; ++i) {
            *(uint4*)&ldsA[(ar + i * 64) * 40 + akc] = paA[i];
            ushort4 hb;
            hb.x = f2b(paB[i].x); hb.y = f2b(paB[i].y); hb.z = f2b(paB[i].z); hb.w = f2b(paB[i].w);
            *(ushort4*)&ldsB[(br + i * 32) * 40 + bc] = hb;
        }
        __syncthreads();

        if (it < 31) {
            const int k0 = (it + 1) * 32;
            #pragma unroll
            for (int i = 0; i < 2; ++i) {
                paA[i] = *(const uint4*)&X[(size_t)(rowA0 + ar + i * 64) * D_MODEL + k0 + akc];
                paB[i] = *(const float4*)&W[(size_t)(rowB0 + br + i * 32) * D_MODEL + k0 + bc];
            }
        }

        bf16x8 af[4], bfr[2];
        #pragma unroll
        for (int t = 0; t < 4; ++t)
            af[t] = ldb8(&ldsA[(wm + t * 16 + l15) * 40 + quad * 8]);
        #pragma unroll
        for (int t = 0; t < 2; ++t)
            bfr[t] = ldb8(&ldsB[(wn + t * 16 + l15) * 40 + quad * 8]);
        #pragma unroll
        for (int mt = 0; mt < 4; ++mt)
            #pragma unroll
            for (int nt = 0; nt < 2; ++nt)
                acc[mt][nt] = __builtin_amdgcn_mfma_f32_16x16x32_bf16(af[mt], bfr[nt], acc[mt][nt], 0, 0, 0);
        __syncthreads();
    }

    #pragma unroll
    for (int nt = 0; nt < 2; ++nt) {
        int n = bx * 64 + wn + nt * 16 + l15;
        float bvv = bias[n];
        #pragma unroll
        for (int mt = 0; mt < 4; ++mt) {
            #pragma unroll
            for (int r = 0; r < 4; ++r) {
                int m = by * 128 + wm + mt * 16 + quad * 4 + r;
                out[(size_t)m * D_MODEL + n] = acc[mt][nt][r] + bvv;
            }
        }
    }
}

// ---------------------------------------------------------------------------
// Flash attention — the proven best config (75 µs): QBLK=16/wave, K/V double
// buffered, LDS 40960 => 4 blocks/CU, grid (32,32) = 1024 = 4*256 zero tail.
// XCD swizzle: blocks sharing a head's K/V (same bh) => same XCD.
// ---------------------------------------------------------------------------
__global__ __launch_bounds__(256, 4) void flash_attn(
    const u16* __restrict__ Q, const u16* __restrict__ K,
    const u16* __restrict__ Vt, const u64* __restrict__ maskbits,
    u16* __restrict__ O)
{
    __shared__ __align__(16) u16 ldsK[2][64 * 64];
    __shared__ __align__(16) u16 ldsV[2][64 * 64];
    __shared__ __align__(16) u16 ldsP[4][16 * 64];

    const int tid  = threadIdx.x;
    const int wv_  = tid >> 6;
    const int lane = tid & 63;
    const int quad = lane >> 4;
    const int l15  = lane & 15;
    const int bh = ((blockIdx.x & 7) << 2) | (blockIdx.y & 3);     // 0..31
    const int qt = ((blockIdx.y >> 2) << 2) | (blockIdx.x >> 3);   // 0..31
    const int b  = bh >> 4, h = bh & 15;
    const int q0 = qt * 64 + wv_ * 16;

    const u16* Qb = Q  + (size_t)bh * SEQ * DEPTH;
    const u16* Kb = K  + (size_t)bh * SEQ * DEPTH;
    const u16* Vb = Vt + (size_t)bh * DEPTH * SEQ;
    const u64* MB = maskbits + (size_t)b * SEQ * (SEQ / 64);

    const int srow = tid >> 3;
    const int sc8  = tid & 7;
    const int swz  = ((sc8 ^ (srow & 7)) * 8);
    const int kdst0 = srow * 64 + swz;
    const int kdst1 = (srow + 32) * 64 + swz;

    const int xk0 = ((quad ^ (l15 & 7)) * 8);
    const int xk1 = (((4 + quad) ^ (l15 & 7)) * 8);

    bf16x8 aq0 = ldb8(&Qb[(q0 + l15) * DEPTH + quad * 8]);
    bf16x8 aq1 = ldb8(&Qb[(q0 + l15) * DEPTH + 32 + quad * 8]);

    bf16x8 vones;
    #pragma unroll
    for (int i = 0; i < 8; ++i) vones[i] = (__bf16)1.0f;

    f32x4 oa[4];
    for (int i = 0; i < 4; ++i) oa[i] = (f32x4){0.f, 0.f, 0.f, 0.f};
    f32x4 lacc = (f32x4){0.f, 0.f, 0.f, 0.f};

    u16* myP = ldsP[wv_];

    int wp[4][4];
    #pragma unroll
    for (int cc = 0; cc < 4; ++cc)
        #pragma unroll
        for (int r = 0; r < 4; ++r) {
            const int row  = quad * 4 + r;
            const int colg = cc * 2 + (l15 >> 3);
            wp[cc][r] = row * 64 + ((colg ^ (row & 7)) * 8) + (l15 & 7);
        }
    const int rp0 = l15 * 64 + ((quad ^ (l15 & 7)) * 8);
    const int rp1 = l15 * 64 + (((4 + quad) ^ (l15 & 7)) * 8);

    uint4 kreg0 = *(const uint4*)&Kb[(size_t)srow * DEPTH + sc8 * 8];
    uint4 kreg1 = *(const uint4*)&Kb[(size_t)(srow + 32) * DEPTH + sc8 * 8];
    uint4 vreg0 = *(const uint4*)&Vb[(size_t)srow * SEQ + sc8 * 8];
    uint4 vreg1 = *(const uint4*)&Vb[(size_t)(srow + 32) * SEQ + sc8 * 8];

    for (int it = 0; it < 32; ++it) {
        const int buf = it & 1;
        u16* Kl = ldsK[buf];
        u16* Vl = ldsV[buf];

        *(uint4*)&Kl[kdst0] = kreg0;
        *(uint4*)&Kl[kdst1] = kreg1;
        *(uint4*)&Vl[kdst0] = vreg0;
        *(uint4*)&Vl[kdst1] = vreg1;
        __syncthreads();

        if (it < 31) {
            const int kb2 = (it + 1) * 64;
            kreg0 = *(const uint4*)&Kb[(size_t)(kb2 + srow) * DEPTH + sc8 * 8];
            kreg1 = *(const uint4*)&Kb[(size_t)(kb2 + srow + 32) * DEPTH + sc8 * 8];
            vreg0 = *(const uint4*)&Vb[(size_t)srow * SEQ + kb2 + sc8 * 8];
            vreg1 = *(const uint4*)&Vb[(size_t)(srow + 32) * SEQ + kb2 + sc8 * 8];
        }

        u32 tlo[4], thi[4];
        #pragma unroll
        for (int r = 0; r < 4; ++r) {
            u64 t = MB[(size_t)(q0 + quad * 4 + r) * (SEQ / 64) + it] >> l15;
            tlo[r] = (u32)t;
            thi[r] = (u32)(t >> 32);
        }

        #pragma unroll
        for (int cc = 0; cc < 4; ++cc) {
            const int row = cc * 16 + l15;
            bf16x8 bk0 = ldb8(&Kl[row * 64 + xk0]);
            bf16x8 bk1 = ldb8(&Kl[row * 64 + xk1]);
            f32x4 z = (f32x4){0.f, 0.f, 0.f, 0.f};
            z = __builtin_amdgcn_mfma_f32_16x16x32_bf16(aq0, bk0, z, 0, 0, 0);
            z = __builtin_amdgcn_mfma_f32_16x16x32_bf16(aq1, bk1, z, 0, 0, 0);
            #pragma unroll
            for (int r = 0; r < 4; ++r) {
                u32 w   = (cc < 2) ? tlo[r] : thi[r];
                u32 bit = (cc & 1) ? ((w >> 16) & 1u) : (w & 1u);
                float e = EXP2(z[r]);            // Q pre-scaled by 0.125*log2(e)
                float p = bit ? 0.f : e;
                myP[wp[cc][r]] = f2b(p);
            }
        }

        __builtin_amdgcn_wave_barrier();
        __builtin_amdgcn_s_waitcnt(0xc07f);   // lgkmcnt(0)
        __builtin_amdgcn_wave_barrier();
        bf16x8 pa0 = ldb8(&myP[rp0]);
        bf16x8 pa1 = ldb8(&myP[rp1]);

        lacc = __builtin_amdgcn_mfma_f32_16x16x32_bf16(pa0, vones, lacc, 0, 0, 0);
        lacc = __builtin_amdgcn_mfma_f32_16x16x32_bf16(pa1, vones, lacc, 0, 0, 0);

        #pragma unroll
        for (int n = 0; n < 4; ++n) {
            const int row = n * 16 + l15;
            bf16x8 bv0 = ldb8(&Vl[row * 64 + xk0]);
            bf16x8 bv1 = ldb8(&Vl[row * 64 + xk1]);
            oa[n] = __builtin_amdgcn_mfma_f32_16x16x32_bf16(pa0, bv0, oa[n], 0, 0, 0);
            oa[n] = __builtin_amdgcn_mfma_f32_16x16x32_bf16(pa1, bv1, oa[n], 0, 0, 0);
        }
    }

    float inv[4];
    #pragma unroll
    for (int r = 0; r < 4; ++r)
        inv[r] = 1.0f / lacc[r];

    #pragma unroll
    for (int n = 0; n < 4; ++n)
        #pragma unroll
        for (int r = 0; r < 4; ++r) {
            int m = q0 + quad * 4 + r;
            O[((size_t)b * SEQ + m) * D_MODEL + h * DEPTH + n * 16 + l15] =
                f2b(oa[n][r] * inv[r]);
        }
}

// ---------------------------------------------------------------------------
extern "C" void kernel_launch(void* const* d_in, const int* in_sizes, int n_in,
                              void* d_out, int out_size, void* d_ws, size_t ws_size,
                              hipStream_t stream) {
    const float* q    = (const float*)d_in[0];
    const float* k    = (const float*)d_in[1];
    const float* v    = (const float*)d_in[2];
    const float* mask = (const float*)d_in[3];
    const float* wq   = (const float*)d_in[4];
    const float* bq   = (const float*)d_in[5];
    const float* wk   = (const float*)d_in[6];
    const float* bk   = (const float*)d_in[7];
    const float* wv   = (const float*)d_in[8];
    const float* bv   = (const float*)d_in[9];
    const float* wo   = (const float*)d_in[10];
    const float* bo   = (const float*)d_in[11];

    // ws (u16 units): [qws 4M][kws 4M][vtws 4M][ows 4M][mbits 512K][wb 4M][xb 12M]
    u16* base = (u16*)d_ws;
    const size_t seg = (size_t)BATCH * NHEADS * SEQ * DEPTH;  // 4M elems
    u16* qws  = base;
    u16* kws  = base + seg;
    u16* vtws = base + 2 * seg;
    u16* ows  = base + 3 * seg;
    u64* mbits = (u64*)(base + 4 * seg);
    u16* wb   = base + 4 * seg + 524288;
    u16* xb   = wb + 4 * 1048576;
    const size_t need_bf16 = (4 * seg + 524288 + 4 * 1048576 + 3 * seg) * 2;
    const bool bf16path = (ws_size >= need_bf16);

    dim3 blk(256);
    hipLaunchKernelGGL(pack_mask, dim3(BATCH * SEQ * (SEQ / 64) / 4), blk, 0, stream, mask, mbits);

    dim3 gp(D_MODEL / 128, MROWS / 128, 3);   // (8, 32, 3)
    if (bf16path) {
        hipLaunchKernelGGL(cvt_bf16, dim3(8192), blk, 0, stream,
                           q, k, v, wq, wk, wv, wo, xb, wb);
        hipLaunchKernelGGL(proj3_bf16, gp, blk, 0, stream,
                           xb, wb, bq, bk, bv, qws, kws, vtws);
    } else {
        hipLaunchKernelGGL(proj3_fused, gp, blk, 0, stream,
                           q, k, v, wq, wk, wv, bq, bk, bv, qws, kws, vtws);
    }

    dim3 ga(32, 32);                          // 1024 blocks = 4/CU
    hipLaunchKernelGGL(flash_attn, ga, blk, 0, stream, qws, kws, vtws, mbits, ows);

    dim3 go(D_MODEL / 64, MROWS / 128);       // (16, 32)
    if (bf16path) {
        hipLaunchKernelGGL(gemm_out_bf16, go, blk, 0, stream, ows, wb + 3 * 1048576, bo, (float*)d_out);
    } else {
        hipLaunchKernelGGL(gemm_out_f32, go, blk, 0, stream, ows, wo, bo, (float*)d_out);
    }
}

// Round 6
// 269.000 us; speedup vs baseline: 1.1001x; 1.0125x over previous
//
#include <hip/hip_runtime.h>

#define D_MODEL 1024
#define NHEADS  16
#define DEPTH   64
#define BATCH   2
#define SEQ     2048
#define MROWS   (BATCH * SEQ)   // 4096
// 0.125 (1/sqrt(DEPTH)) * log2(e): folded into Q projection; flash uses raw v_exp_f32 (exp2)
#define QSCALE  0.18033688011112042f

typedef unsigned short u16;
typedef unsigned int   u32;
typedef unsigned long long u64;
typedef __bf16 bf16x8 __attribute__((ext_vector_type(8)));
typedef float  f32x4  __attribute__((ext_vector_type(4)));

#if __has_builtin(__builtin_amdgcn_exp2f)
#define EXP2(x) __builtin_amdgcn_exp2f(x)
#else
#define EXP2(x) exp2f(x)
#endif

__device__ __forceinline__ u16 f2b(float f) {
    return __builtin_bit_cast(u16, static_cast<__bf16>(f));   // v_cvt RNE
}
__device__ __forceinline__ bf16x8 ldb8(const u16* p) {
    return __builtin_bit_cast(bf16x8, *(const uint4*)p);
}
// async global->LDS, 16B per lane; LDS dest is wave-uniform base + lane*16
__device__ __forceinline__ void gload16(const u16* g, u16* l) {
    __builtin_amdgcn_global_load_lds(
        (const __attribute__((address_space(1))) void*)g,
        (__attribute__((address_space(3))) void*)l, 16, 0, 0);
}

// ---------------------------------------------------------------------------
// Pack mask f32 [B,S,S] (1 => masked) into bit-words: word (b*S+q)*32 + k64.
// ---------------------------------------------------------------------------
__global__ __launch_bounds__(256) void pack_mask(
    const float* __restrict__ mask, u64* __restrict__ bits)
{
    const int w    = blockIdx.x * 4 + (threadIdx.x >> 6);
    const int lane = threadIdx.x & 63;
    float m = mask[(size_t)w * 64 + lane];
    u64 b = __ballot(m > 0.5f);
    if (lane == 0) bits[w] = b;
}

// ---------------------------------------------------------------------------
// fp32 -> bf16 conversion: q,k,v (3 x 4M elems) then wq,wk,wv,wo (4 x 1M).
// ---------------------------------------------------------------------------
__global__ __launch_bounds__(256) void cvt_bf16(
    const float* __restrict__ q, const float* __restrict__ k, const float* __restrict__ v,
    const float* __restrict__ wq, const float* __restrict__ wk, const float* __restrict__ wv,
    const float* __restrict__ wo,
    u16* __restrict__ xb, u16* __restrict__ wb)
{
    const size_t e = ((size_t)blockIdx.x * 256 + threadIdx.x) * 8;
    const float* src;
    u16* dst;
    size_t off;
    if (e < 12582912) {                      // 3 * 4M: q,k,v
        const int a = (int)(e >> 22);
        off = e & 4194303;
        src = (a == 0) ? q : (a == 1) ? k : v;
        dst = xb + ((size_t)a << 22) + off;
    } else {                                 // 4 * 1M: wq,wk,wv,wo
        const size_t e2 = e - 12582912;
        const int a = (int)(e2 >> 20);
        off = e2 & 1048575;
        src = (a == 0) ? wq : (a == 1) ? wk : (a == 2) ? wv : wo;
        dst = wb + ((size_t)a << 20) + off;
    }
    const float4 f0 = *(const float4*)(src + off);
    const float4 f1 = *(const float4*)(src + off + 4);
    uint4 o;
    o.x = (u32)f2b(f0.x) | ((u32)f2b(f0.y) << 16);
    o.y = (u32)f2b(f0.z) | ((u32)f2b(f0.w) << 16);
    o.z = (u32)f2b(f1.x) | ((u32)f2b(f1.y) << 16);
    o.w = (u32)f2b(f1.z) | ((u32)f2b(f1.w) << 16);
    *(uint4*)dst = o;
}

// ---------------------------------------------------------------------------
// Merged Q/K/V projection, pure-bf16 inputs, m97 structure.
// Grid (8,32,3) = 768 blocks = 3/CU exactly. LDS 32 KB.
// z==2 epilogue: transpose the 128x128 output tile in LDS (reusing the
// staging buffer, XOR-swizzled) => coalesced dwordx4 V^T stores.
// ---------------------------------------------------------------------------
__global__ __launch_bounds__(256, 3) void proj3_bf16(
    const u16* __restrict__ xb, const u16* __restrict__ wb,
    const float* __restrict__ bq, const float* __restrict__ bk, const float* __restrict__ bv,
    u16* __restrict__ qws, u16* __restrict__ kws, u16* __restrict__ vtws)
{
    __shared__ __align__(16) u16 smem[16384];   // 32 KB: la | lb, reused as 128x128 transpose buf
    u16 (*la)[4096] = reinterpret_cast<u16(*)[4096]>(smem);
    u16 (*lb)[4096] = reinterpret_cast<u16(*)[4096]>(smem + 8192);

    const int z = blockIdx.z;
    const u16* X = xb + ((size_t)z << 22);
    const u16* W = wb + ((size_t)z << 20);
    const float* Bi = (z == 0) ? bq : (z == 1) ? bk : bv;
    u16* dst       = (z == 0) ? qws : (z == 1) ? kws : vtws;

    const int tid  = threadIdx.x;
    const int wv_  = tid >> 6;
    const int lane = tid & 63;
    const int quad = lane >> 4;
    const int l15  = lane & 15;
    const int bx = blockIdx.y >> 2;                            // 0..7
    const int by = (blockIdx.x << 2) | (blockIdx.y & 3);       // 0..31
    const int wm = (wv_ >> 1) * 64;
    const int wn = (wv_ & 1) * 64;

    f32x4 acc[4][4];
    for (int i = 0; i < 4; ++i)
        for (int j = 0; j < 4; ++j)
            acc[i][j] = (f32x4){0.f, 0.f, 0.f, 0.f};

    const int rowA0 = by * 128;
    const int rowB0 = bx * 128;

    const int strow = tid >> 2;
    const int stcol = (tid & 3) * 8;
    const u16* gA0 = &X[(size_t)(rowA0 + strow) * D_MODEL + stcol];
    const u16* gA1 = gA0 + (size_t)64 * D_MODEL;
    const u16* gB0 = &W[(size_t)(rowB0 + strow) * D_MODEL + stcol];
    const u16* gB1 = gB0 + (size_t)64 * D_MODEL;
    const int l0 = tid * 8, l1 = 2048 + tid * 8;

    gload16(gA0, &la[0][l0]);
    gload16(gA1, &la[0][l1]);
    gload16(gB0, &lb[0][l0]);
    gload16(gB1, &lb[0][l1]);
    __syncthreads();

    for (int t = 0; t < 32; ++t) {
        const int buf = t & 1;
        if (t < 31) {
            const int ko = (t + 1) * 32;
            gload16(gA0 + ko, &la[buf ^ 1][l0]);
            gload16(gA1 + ko, &la[buf ^ 1][l1]);
            gload16(gB0 + ko, &lb[buf ^ 1][l0]);
            gload16(gB1 + ko, &lb[buf ^ 1][l1]);
        }
        bf16x8 af[4], bfr[4];
        #pragma unroll
        for (int tt = 0; tt < 4; ++tt) {
            af[tt]  = ldb8(&la[buf][(wm + tt * 16 + l15) * 32 + quad * 8]);
            bfr[tt] = ldb8(&lb[buf][(wn + tt * 16 + l15) * 32 + quad * 8]);
        }
        #pragma unroll
        for (int mt = 0; mt < 4; ++mt)
            #pragma unroll
            for (int nt = 0; nt < 4; ++nt)
                acc[mt][nt] = __builtin_amdgcn_mfma_f32_16x16x32_bf16(af[mt], bfr[nt], acc[mt][nt], 0, 0, 0);
        __syncthreads();
    }

    if (z != 2) {
        #pragma unroll
        for (int nt = 0; nt < 4; ++nt) {
            int n = rowB0 + wn + nt * 16 + l15;
            float bvv = Bi[n];
            int h = n >> 6, d = n & 63;
            #pragma unroll
            for (int mt = 0; mt < 4; ++mt) {
                #pragma unroll
                for (int r = 0; r < 4; ++r) {
                    int m = rowA0 + wm + mt * 16 + quad * 4 + r;
                    float c = acc[mt][nt][r] + bvv;
                    if (z == 0) c *= QSCALE;
                    int b = m >> 11, s = m & (SEQ - 1);
                    dst[(((size_t)(b * NHEADS + h) * SEQ) + s) * DEPTH + d] = f2b(c);
                }
            }
        }
    } else {
        // stage C^T (128 n x 128 m) into swizzled LDS, then coalesced stores.
        #pragma unroll
        for (int nt = 0; nt < 4; ++nt) {
            const int nl = wn + nt * 16 + l15;
            const float bvv = Bi[rowB0 + nl];
            #pragma unroll
            for (int mt = 0; mt < 4; ++mt) {
                #pragma unroll
                for (int r2 = 0; r2 < 4; r2 += 2) {
                    const int ml = wm + mt * 16 + quad * 4 + r2;   // even
                    u32 pk = (u32)f2b(acc[mt][nt][r2] + bvv)
                           | ((u32)f2b(acc[mt][nt][r2 + 1] + bvv) << 16);
                    const int g = ml >> 3;
                    *(u32*)&smem[nl * 128 + (((g ^ (nl & 15)) << 3) | (ml & 7))] = pk;
                }
            }
        }
        __syncthreads();
        const int nl  = tid >> 1;                 // local n row 0..127
        const int cc0 = (tid & 1) * 64;           // m half
        const int n   = rowB0 + nl;
        const int bb  = rowA0 >> 11;              // uniform per block
        u16* dbase = dst + (((size_t)(bb * NHEADS + (n >> 6)) * DEPTH) + (n & 63)) * SEQ
                   + (rowA0 & (SEQ - 1)) + cc0;
        #pragma unroll
        for (int j = 0; j < 8; ++j) {
            const int g = (tid & 1) * 8 + j;
            *(uint4*)&dbase[j * 8] =
                *(const uint4*)&smem[nl * 128 + ((g ^ (nl & 15)) << 3)];
        }
    }
}

// ---------------------------------------------------------------------------
// Fallback fused projection (fp32 in-kernel cvt) for small workspaces.
// ---------------------------------------------------------------------------
__global__ __launch_bounds__(256, 3) void proj3_fused(
    const float* __restrict__ q, const float* __restrict__ k, const float* __restrict__ v,
    const float* __restrict__ wq, const float* __restrict__ wk, const float* __restrict__ wv,
    const float* __restrict__ bq, const float* __restrict__ bk, const float* __restrict__ bv,
    u16* __restrict__ qws, u16* __restrict__ kws, u16* __restrict__ vtws)
{
    __shared__ __align__(16) u16 ldsA[128 * 40];
    __shared__ __align__(16) u16 ldsB[128 * 40];

    const int z = blockIdx.z;
    const float* X  = (z == 0) ? q  : (z == 1) ? k  : v;
    const float* W  = (z == 0) ? wq : (z == 1) ? wk : wv;
    const float* Bi = (z == 0) ? bq : (z == 1) ? bk : bv;
    u16* dst        = (z == 0) ? qws : (z == 1) ? kws : vtws;

    const int tid  = threadIdx.x;
    const int wv_  = tid >> 6;
    const int lane = tid & 63;
    const int quad = lane >> 4;
    const int l15  = lane & 15;
    const int bx = blockIdx.y >> 2;
    const int by = (blockIdx.x << 2) | (blockIdx.y & 3);
    const int wm = (wv_ >> 1) * 64;
    const int wn = (wv_ & 1) * 64;

    f32x4 acc[4][4];
    for (int i = 0; i < 4; ++i)
        for (int j = 0; j < 4; ++j)
            acc[i][j] = (f32x4){0.f, 0.f, 0.f, 0.f};

    const int rowA0 = by * 128;
    const int rowB0 = bx * 128;

    const int sr = tid >> 3;
    const int sc = (tid & 7) * 4;

    float4 pa[4], pb[4];
    #pragma unroll
    for (int i = 0; i < 4; ++i) {
        pa[i] = *(const float4*)&X[(size_t)(rowA0 + sr + i * 32) * D_MODEL + sc];
        pb[i] = *(const float4*)&W[(size_t)(rowB0 + sr + i * 32) * D_MODEL + sc];
    }

    for (int it = 0; it < 32; ++it) {
        #pragma unroll
        for (int i = 0; i < 4; ++i) {
            ushort4 ha, hb;
            ha.x = f2b(pa[i].x); ha.y = f2b(pa[i].y); ha.z = f2b(pa[i].z); ha.w = f2b(pa[i].w);
            hb.x = f2b(pb[i].x); hb.y = f2b(pb[i].y); hb.z = f2b(pb[i].z); hb.w = f2b(pb[i].w);
            *(ushort4*)&ldsA[(sr + i * 32) * 40 + sc] = ha;
            *(ushort4*)&ldsB[(sr + i * 32) * 40 + sc] = hb;
        }
        __syncthreads();

        if (it < 31) {
            const int k0 = (it + 1) * 32;
            #pragma unroll
            for (int i = 0; i < 4; ++i) {
                pa[i] = *(const float4*)&X[(size_t)(rowA0 + sr + i * 32) * D_MODEL + k0 + sc];
                pb[i] = *(const float4*)&W[(size_t)(rowB0 + sr + i * 32) * D_MODEL + k0 + sc];
            }
        }

        bf16x8 af[4], bfr[4];
        #pragma unroll
        for (int t = 0; t < 4; ++t) {
            af[t]  = ldb8(&ldsA[(wm + t * 16 + l15) * 40 + quad * 8]);
            bfr[t] = ldb8(&ldsB[(wn + t * 16 + l15) * 40 + quad * 8]);
        }
        #pragma unroll
        for (int mt = 0; mt < 4; ++mt)
            #pragma unroll
            for (int nt = 0; nt < 4; ++nt)
                acc[mt][nt] = __builtin_amdgcn_mfma_f32_16x16x32_bf16(af[mt], bfr[nt], acc[mt][nt], 0, 0, 0);
        __syncthreads();
    }

    #pragma unroll
    for (int nt = 0; nt < 4; ++nt) {
        int n = bx * 128 + wn + nt * 16 + l15;
        float bvv = Bi[n];
        int h = n >> 6, d = n & 63;
        #pragma unroll
        for (int mt = 0; mt < 4; ++mt) {
            #pragma unroll
            for (int r = 0; r < 4; ++r) {
                int m = by * 128 + wm + mt * 16 + quad * 4 + r;
                float c = acc[mt][nt][r] + bvv;
                if (z == 0) c *= QSCALE;
                int b = m >> 11, s = m & (SEQ - 1);
                if (z != 2)
                    dst[(((size_t)(b * NHEADS + h) * SEQ) + s) * DEPTH + d] = f2b(c);
                else
                    dst[(((size_t)(b * NHEADS + h) * DEPTH) + d) * SEQ + s] = f2b(c);
            }
        }
    }
}

// ---------------------------------------------------------------------------
// Output projection, pure-bf16 inputs, m97 structure. Grid (16,32) = 2/CU.
// ---------------------------------------------------------------------------
__global__ __launch_bounds__(256, 2) void gemm_out_bf16(
    const u16* __restrict__ X, const u16* __restrict__ W,
    const float* __restrict__ bias, float* __restrict__ out)
{
    __shared__ __align__(16) u16 la[2][128 * 32];
    __shared__ __align__(16) u16 lb[2][64 * 32];

    const int tid  = threadIdx.x;
    const int wv_  = tid >> 6;
    const int lane = tid & 63;
    const int quad = lane >> 4;
    const int l15  = lane & 15;
    const int bx = ((blockIdx.y >> 2) << 1) | (blockIdx.x >> 3);   // 0..15
    const int by = ((blockIdx.x & 7) << 2) | (blockIdx.y & 3);     // 0..31
    const int wm = (wv_ >> 1) * 64;
    const int wn = (wv_ & 1) * 32;

    f32x4 acc[4][2];
    for (int i = 0; i < 4; ++i)
        for (int j = 0; j < 2; ++j)
            acc[i][j] = (f32x4){0.f, 0.f, 0.f, 0.f};

    const int rowA0 = by * 128;
    const int rowB0 = bx * 64;

    const int strow = tid >> 2;
    const int stcol = (tid & 3) * 8;
    const u16* gA0 = &X[(size_t)(rowA0 + strow) * D_MODEL + stcol];
    const u16* gA1 = gA0 + (size_t)64 * D_MODEL;
    const u16* gB0 = &W[(size_t)(rowB0 + strow) * D_MODEL + stcol];
    const int l0 = tid * 8, l1 = 2048 + tid * 8;

    gload16(gA0, &la[0][l0]);
    gload16(gA1, &la[0][l1]);
    gload16(gB0, &lb[0][l0]);
    __syncthreads();

    for (int t = 0; t < 32; ++t) {
        const int buf = t & 1;
        if (t < 31) {
            const int ko = (t + 1) * 32;
            gload16(gA0 + ko, &la[buf ^ 1][l0]);
            gload16(gA1 + ko, &la[buf ^ 1][l1]);
            gload16(gB0 + ko, &lb[buf ^ 1][l0]);
        }
        bf16x8 af[4], bfr[2];
        #pragma unroll
        for (int tt = 0; tt < 4; ++tt)
            af[tt] = ldb8(&la[buf][(wm + tt * 16 + l15) * 32 + quad * 8]);
        #pragma unroll
        for (int tt = 0; tt < 2; ++tt)
            bfr[tt] = ldb8(&lb[buf][(wn + tt * 16 + l15) * 32 + quad * 8]);
        #pragma unroll
        for (int mt = 0; mt < 4; ++mt)
            #pragma unroll
            for (int nt = 0; nt < 2; ++nt)
                acc[mt][nt] = __builtin_amdgcn_mfma_f32_16x16x32_bf16(af[mt], bfr[nt], acc[mt][nt], 0, 0, 0);
        __syncthreads();
    }

    #pragma unroll
    for (int nt = 0; nt < 2; ++nt) {
        int n = bx * 64 + wn + nt * 16 + l15;
        float bvv = bias[n];
        #pragma unroll
        for (int mt = 0; mt < 4; ++mt) {
            #pragma unroll
            for (int r = 0; r < 4; ++r) {
                int m = by * 128 + wm + mt * 16 + quad * 4 + r;
                out[(size_t)m * D_MODEL + n] = acc[mt][nt][r] + bvv;
            }
        }
    }
}

// ---------------------------------------------------------------------------
// Fallback output projection (fp32 W, reg-staged).
// ---------------------------------------------------------------------------
__global__ __launch_bounds__(256) void gemm_out_f32(
    const u16* __restrict__ X, const float* __restrict__ W,
    const float* __restrict__ bias, float* __restrict__ out)
{
    __shared__ __align__(16) u16 ldsA[128 * 40];
    __shared__ __align__(16) u16 ldsB[64 * 40];

    const int tid  = threadIdx.x;
    const int wv_  = tid >> 6;
    const int lane = tid & 63;
    const int quad = lane >> 4;
    const int l15  = lane & 15;
    const int bx = ((blockIdx.y >> 2) << 1) | (blockIdx.x >> 3);   // 0..15
    const int by = ((blockIdx.x & 7) << 2) | (blockIdx.y & 3);     // 0..31
    const int wm = (wv_ >> 1) * 64;
    const int wn = (wv_ & 1) * 32;

    f32x4 acc[4][2];
    for (int i = 0; i < 4; ++i)
        for (int j = 0; j < 2; ++j)
            acc[i][j] = (f32x4){0.f, 0.f, 0.f, 0.f};

    const int rowA0 = by * 128;
    const int rowB0 = bx * 64;

    const int ar = tid >> 2, akc = (tid & 3) * 8;
    const int br = tid >> 3, bc = (tid & 7) * 4;

    uint4  paA[2];
    float4 paB[2];
    #pragma unroll
    for (int i = 0; i < 2; ++i) {
        paA[i] = *(const uint4*)&X[(size_t)(rowA0 + ar + i * 64) * D_MODEL + akc];
        paB[i] = *(const float4*)&W[(size_t)(rowB0 + br + i * 32) * D_MODEL + bc];
    }

    for (int it = 0; it < 32; ++it) {
        #pragma unroll
        for (int i = 0; i < 2; ++i) {
            *(uint4*)&ldsA[(ar + i * 64) * 40 + akc] = paA[i];
            ushort4 hb;
            hb.x = f2b(paB[i].x); hb.y = f2b(paB[i].y); hb.z = f2b(paB[i].z); hb.w = f2b(paB[i].w);
            *(ushort4*)&ldsB[(br + i * 32) * 40 + bc] = hb;
        }
        __syncthreads();

        if (it < 31) {
            const int k0 = (it + 1) * 32;
            #pragma unroll
            for (int i = 0; i < 2; ++i) {
                paA[i] = *(const uint4*)&X[(size_t)(rowA0 + ar + i * 64) * D_MODEL + k0 + akc];
                paB[i] = *(const float4*)&W[(size_t)(rowB0 + br + i * 32) * D_MODEL + k0 + bc];
            }
        }

        bf16x8 af[4], bfr[2];
        #pragma unroll
        for (int t = 0; t < 4; ++t)
            af[t] = ldb8(&ldsA[(wm + t * 16 + l15) * 40 + quad * 8]);
        #pragma unroll
        for (int t = 0; t < 2; ++t)
            bfr[t] = ldb8(&ldsB[(wn + t * 16 + l15) * 40 + quad * 8]);
        #pragma unroll
        for (int mt = 0; mt < 4; ++mt)
            #pragma unroll
            for (int nt = 0; nt < 2; ++nt)
                acc[mt][nt] = __builtin_amdgcn_mfma_f32_16x16x32_bf16(af[mt], bfr[nt], acc[mt][nt], 0, 0, 0);
        __syncthreads();
    }

    #pragma unroll
    for (int nt = 0; nt < 2; ++nt) {
        int n = bx * 64 + wn + nt * 16 + l15;
        float bvv = bias[n];
        #pragma unroll
        for (int mt = 0; mt < 4; ++mt) {
            #pragma unroll
            for (int r = 0; r < 4; ++r) {
                int m = by * 128 + wm + mt * 16 + quad * 4 + r;
                out[(size_t)m * D_MODEL + n] = acc[mt][nt][r] + bvv;
            }
        }
    }
}

// ---------------------------------------------------------------------------
// Flash attention. QBLK=16/wave, K/V double-buffered, LDS 40960 => 4 blk/CU,
// grid (32,32) = 1024 = 4*256 zero tail. XCD swizzle: same bh => same XCD.
// This round:
//  - K/V staged via global_load_lds (linear LDS dest, INVERSE-swizzled per-lane
//    global source; read side keeps the XOR addresses) => no ds_write_b128,
//    no global->reg->LDS round trip.
//  - Swapped QK^T: z = mfma(K, Q) => lane holds 4 contiguous k-cols of ONE
//    q-row (q = q0+l15) => P written as 4x ds_write_b64 instead of 16x b16,
//    and 1 mask u64 load/iter instead of 4. P read side unchanged.
// ---------------------------------------------------------------------------
__global__ __launch_bounds__(256, 4) void flash_attn(
    const u16* __restrict__ Q, const u16* __restrict__ K,
    const u16* __restrict__ Vt, const u64* __restrict__ maskbits,
    u16* __restrict__ O)
{
    __shared__ __align__(16) u16 ldsK[2][64 * 64];
    __shared__ __align__(16) u16 ldsV[2][64 * 64];
    __shared__ __align__(16) u16 ldsP[4][16 * 64];

    const int tid  = threadIdx.x;
    const int wv_  = tid >> 6;
    const int lane = tid & 63;
    const int quad = lane >> 4;
    const int l15  = lane & 15;
    const int bh = ((blockIdx.x & 7) << 2) | (blockIdx.y & 3);     // 0..31
    const int qt = ((blockIdx.y >> 2) << 2) | (blockIdx.x >> 3);   // 0..31
    const int b  = bh >> 4, h = bh & 15;
    const int q0 = qt * 64 + wv_ * 16;

    const u16* Qb = Q  + (size_t)bh * SEQ * DEPTH;
    const u16* Kb = K  + (size_t)bh * SEQ * DEPTH;
    const u16* Vb = Vt + (size_t)bh * DEPTH * SEQ;
    const u64* MB = maskbits + (size_t)b * SEQ * (SEQ / 64);

    // gload staging: LDS linear slot tid*16B = row (tid>>3), group (tid&7);
    // source column group inverse-swizzled so swizzled READS see logical data.
    const int sr8  = tid >> 3;                 // 0..31
    const int sg   = tid & 7;
    const int scol = ((sg ^ (sr8 & 7)) * 8);   // (sr8+32)&7 == sr8&7
    const u16* kS0 = &Kb[(size_t)sr8 * DEPTH + scol];
    const u16* kS1 = &Kb[(size_t)(sr8 + 32) * DEPTH + scol];
    const u16* vS0 = &Vb[(size_t)sr8 * SEQ + scol];
    const u16* vS1 = &Vb[(size_t)(sr8 + 32) * SEQ + scol];
    const int ld0 = tid * 8, ld1 = 2048 + tid * 8;

    const int xk0 = ((quad ^ (l15 & 7)) * 8);
    const int xk1 = (((4 + quad) ^ (l15 & 7)) * 8);

    bf16x8 aq0 = ldb8(&Qb[(q0 + l15) * DEPTH + quad * 8]);
    bf16x8 aq1 = ldb8(&Qb[(q0 + l15) * DEPTH + 32 + quad * 8]);

    bf16x8 vones;
    #pragma unroll
    for (int i = 0; i < 8; ++i) vones[i] = (__bf16)1.0f;

    f32x4 oa[4];
    for (int i = 0; i < 4; ++i) oa[i] = (f32x4){0.f, 0.f, 0.f, 0.f};
    f32x4 lacc = (f32x4){0.f, 0.f, 0.f, 0.f};

    u16* myP = ldsP[wv_];

    // P write (swapped layout): row = q-local = l15, cols cc*16+quad*4+0..3
    // => one b64 per cc at swizzled addr; r=0..3 contiguous within a group.
    int wpq[4];
    #pragma unroll
    for (int cc = 0; cc < 4; ++cc) {
        const int g = cc * 2 + (quad >> 1);
        wpq[cc] = l15 * 64 + ((g ^ (l15 & 7)) * 8) + (quad & 1) * 4;
    }
    // P read (A-fragment, unchanged)
    const int rp0 = l15 * 64 + ((quad ^ (l15 & 7)) * 8);
    const int rp1 = l15 * 64 + (((4 + quad) ^ (l15 & 7)) * 8);

    // prologue: stage tile 0 into buffer 0
    gload16(kS0, &ldsK[0][ld0]);
    gload16(kS1, &ldsK[0][ld1]);
    gload16(vS0, &ldsV[0][ld0]);
    gload16(vS1, &ldsV[0][ld1]);
    __syncthreads();

    for (int it = 0; it < 32; ++it) {
        const int buf = it & 1;
        const u16* Kl = ldsK[buf];
        const u16* Vl = ldsV[buf];

        if (it < 31) {
            const int kb2 = (it + 1) * 64;
            gload16(kS0 + (size_t)kb2 * DEPTH, &ldsK[buf ^ 1][ld0]);
            gload16(kS1 + (size_t)kb2 * DEPTH, &ldsK[buf ^ 1][ld1]);
            gload16(vS0 + kb2, &ldsV[buf ^ 1][ld0]);
            gload16(vS1 + kb2, &ldsV[buf ^ 1][ld1]);
        }

        const u64 t = MB[(size_t)(q0 + l15) * (SEQ / 64) + it];
        const u32 tlo = (u32)t, thi = (u32)(t >> 32);

        #pragma unroll
        for (int cc = 0; cc < 4; ++cc) {
            const int row = cc * 16 + l15;
            bf16x8 bk0 = ldb8(&Kl[row * 64 + xk0]);
            bf16x8 bk1 = ldb8(&Kl[row * 64 + xk1]);
            // swapped: C[m=kv row][n=q col] => lane holds q = q0+l15,
            // k = cc*16 + quad*4 + r
            f32x4 z = (f32x4){0.f, 0.f, 0.f, 0.f};
            z = __builtin_amdgcn_mfma_f32_16x16x32_bf16(bk0, aq0, z, 0, 0, 0);
            z = __builtin_amdgcn_mfma_f32_16x16x32_bf16(bk1, aq1, z, 0, 0, 0);
            const u32 w = (cc & 2) ? thi : tlo;
            float p[4];
            #pragma unroll
            for (int r = 0; r < 4; ++r) {
                const u32 bit = (w >> ((cc & 1) * 16 + quad * 4 + r)) & 1u;
                float e = EXP2(z[r]);            // Q pre-scaled by 0.125*log2(e)
                p[r] = bit ? 0.f : e;
            }
            uint2 pk;
            pk.x = (u32)f2b(p[0]) | ((u32)f2b(p[1]) << 16);
            pk.y = (u32)f2b(p[2]) | ((u32)f2b(p[3]) << 16);
            *(uint2*)&myP[wpq[cc]] = pk;
        }

        __builtin_amdgcn_wave_barrier();
        __builtin_amdgcn_s_waitcnt(0xc07f);   // lgkmcnt(0)
        __builtin_amdgcn_wave_barrier();
        bf16x8 pa0 = ldb8(&myP[rp0]);
        bf16x8 pa1 = ldb8(&myP[rp1]);

        lacc = __builtin_amdgcn_mfma_f32_16x16x32_bf16(pa0, vones, lacc, 0, 0, 0);
        lacc = __builtin_amdgcn_mfma_f32_16x16x32_bf16(pa1, vones, lacc, 0, 0, 0);

        #pragma unroll
        for (int n = 0; n < 4; ++n) {
            const int row = n * 16 + l15;
            bf16x8 bv0 = ldb8(&Vl[row * 64 + xk0]);
            bf16x8 bv1 = ldb8(&Vl[row * 64 + xk1]);
            oa[n] = __builtin_amdgcn_mfma_f32_16x16x32_bf16(pa0, bv0, oa[n], 0, 0, 0);
            oa[n] = __builtin_amdgcn_mfma_f32_16x16x32_bf16(pa1, bv1, oa[n], 0, 0, 0);
        }

        __syncthreads();   // drains vmcnt: next tile staged; this tile's reads done
    }

    float inv[4];
    #pragma unroll
    for (int r = 0; r < 4; ++r)
        inv[r] = 1.0f / lacc[r];

    #pragma unroll
    for (int n = 0; n < 4; ++n)
        #pragma unroll
        for (int r = 0; r < 4; ++r) {
            int m = q0 + quad * 4 + r;
            O[((size_t)b * SEQ + m) * D_MODEL + h * DEPTH + n * 16 + l15] =
                f2b(oa[n][r] * inv[r]);
        }
}

// ---------------------------------------------------------------------------
extern "C" void kernel_launch(void* const* d_in, const int* in_sizes, int n_in,
                              void* d_out, int out_size, void* d_ws, size_t ws_size,
                              hipStream_t stream) {
    const float* q    = (const float*)d_in[0];
    const float* k    = (const float*)d_in[1];
    const float* v    = (const float*)d_in[2];
    const float* mask = (const float*)d_in[3];
    const float* wq   = (const float*)d_in[4];
    const float* bq   = (const float*)d_in[5];
    const float* wk   = (const float*)d_in[6];
    const float* bk   = (const float*)d_in[7];
    const float* wv   = (const float*)d_in[8];
    const float* bv   = (const float*)d_in[9];
    const float* wo   = (const float*)d_in[10];
    const float* bo   = (const float*)d_in[11];

    // ws (u16 units): [qws 4M][kws 4M][vtws 4M][ows 4M][mbits 512K][wb 4M][xb 12M]
    u16* base = (u16*)d_ws;
    const size_t seg = (size_t)BATCH * NHEADS * SEQ * DEPTH;  // 4M elems
    u16* qws  = base;
    u16* kws  = base + seg;
    u16* vtws = base + 2 * seg;
    u16* ows  = base + 3 * seg;
    u64* mbits = (u64*)(base + 4 * seg);
    u16* wb   = base + 4 * seg + 524288;
    u16* xb   = wb + 4 * 1048576;
    const size_t need_bf16 = (4 * seg + 524288 + 4 * 1048576 + 3 * seg) * 2;
    const bool bf16path = (ws_size >= need_bf16);

    dim3 blk(256);
    hipLaunchKernelGGL(pack_mask, dim3(BATCH * SEQ * (SEQ / 64) / 4), blk, 0, stream, mask, mbits);

    dim3 gp(D_MODEL / 128, MROWS / 128, 3);   // (8, 32, 3)
    if (bf16path) {
        hipLaunchKernelGGL(cvt_bf16, dim3(8192), blk, 0, stream,
                           q, k, v, wq, wk, wv, wo, xb, wb);
        hipLaunchKernelGGL(proj3_bf16, gp, blk, 0, stream,
                           xb, wb, bq, bk, bv, qws, kws, vtws);
    } else {
        hipLaunchKernelGGL(proj3_fused, gp, blk, 0, stream,
                           q, k, v, wq, wk, wv, bq, bk, bv, qws, kws, vtws);
    }

    dim3 ga(32, 32);                          // 1024 blocks = 4/CU
    hipLaunchKernelGGL(flash_attn, ga, blk, 0, stream, qws, kws, vtws, mbits, ows);

    dim3 go(D_MODEL / 64, MROWS / 128);       // (16, 32)
    if (bf16path) {
        hipLaunchKernelGGL(gemm_out_bf16, go, blk, 0, stream, ows, wb + 3 * 1048576, bo, (float*)d_out);
    } else {
        hipLaunchKernelGGL(gemm_out_f32, go, blk, 0, stream, ows, wo, bo, (float*)d_out);
    }
}

// Round 7
// 268.986 us; speedup vs baseline: 1.1001x; 1.0000x over previous
//
#include <hip/hip_runtime.h>

#define D_MODEL 1024
#define NHEADS  16
#define DEPTH   64
#define BATCH   2
#define SEQ     2048
#define MROWS   (BATCH * SEQ)   // 4096
// 0.125 (1/sqrt(DEPTH)) * log2(e): folded into Q projection; flash uses raw v_exp_f32 (exp2)
#define QSCALE  0.18033688011112042f

typedef unsigned short u16;
typedef unsigned int   u32;
typedef unsigned long long u64;
typedef __bf16 bf16x8 __attribute__((ext_vector_type(8)));
typedef float  f32x4  __attribute__((ext_vector_type(4)));

#if __has_builtin(__builtin_amdgcn_exp2f)
#define EXP2(x) __builtin_amdgcn_exp2f(x)
#else
#define EXP2(x) exp2f(x)
#endif

__device__ __forceinline__ u16 f2b(float f) {
    return __builtin_bit_cast(u16, static_cast<__bf16>(f));   // v_cvt RNE
}
__device__ __forceinline__ bf16x8 ldb8(const u16* p) {
    return __builtin_bit_cast(bf16x8, *(const uint4*)p);
}
// async global->LDS, 16B per lane; LDS dest is wave-uniform base + lane*16
__device__ __forceinline__ void gload16(const u16* g, u16* l) {
    __builtin_amdgcn_global_load_lds(
        (const __attribute__((address_space(1))) void*)g,
        (__attribute__((address_space(3))) void*)l, 16, 0, 0);
}

// ---------------------------------------------------------------------------
// Pack mask f32 [B,S,S] (1 => masked) into bit-words (fallback path only).
// ---------------------------------------------------------------------------
__global__ __launch_bounds__(256) void pack_mask(
    const float* __restrict__ mask, u64* __restrict__ bits)
{
    const int w    = blockIdx.x * 4 + (threadIdx.x >> 6);
    const int lane = threadIdx.x & 63;
    float m = mask[(size_t)w * 64 + lane];
    u64 b = __ballot(m > 0.5f);
    if (lane == 0) bits[w] = b;
}

// ---------------------------------------------------------------------------
// Fused streaming pass:
//  blocks [0, 8192): fp32->bf16 cvt of q,k,v (3x4M) + wq,wk,wv,wo (4x1M)
//  blocks [8192, 8192+32768): mask bit-pack (independent, saves a launch)
// ---------------------------------------------------------------------------
__global__ __launch_bounds__(256) void cvt_pack(
    const float* __restrict__ q, const float* __restrict__ k, const float* __restrict__ v,
    const float* __restrict__ wq, const float* __restrict__ wk, const float* __restrict__ wv,
    const float* __restrict__ wo, const float* __restrict__ mask,
    u16* __restrict__ xb, u16* __restrict__ wb, u64* __restrict__ bits)
{
    if (blockIdx.x >= 8192) {
        const int w    = (blockIdx.x - 8192) * 4 + (threadIdx.x >> 6);
        const int lane = threadIdx.x & 63;
        float m = mask[(size_t)w * 64 + lane];
        u64 b = __ballot(m > 0.5f);
        if (lane == 0) bits[w] = b;
        return;
    }
    const size_t e = ((size_t)blockIdx.x * 256 + threadIdx.x) * 8;
    const float* src;
    u16* dst;
    size_t off;
    if (e < 12582912) {                      // 3 * 4M: q,k,v
        const int a = (int)(e >> 22);
        off = e & 4194303;
        src = (a == 0) ? q : (a == 1) ? k : v;
        dst = xb + ((size_t)a << 22) + off;
    } else {                                 // 4 * 1M: wq,wk,wv,wo
        const size_t e2 = e - 12582912;
        const int a = (int)(e2 >> 20);
        off = e2 & 1048575;
        src = (a == 0) ? wq : (a == 1) ? wk : (a == 2) ? wv : wo;
        dst = wb + ((size_t)a << 20) + off;
    }
    const float4 f0 = *(const float4*)(src + off);
    const float4 f1 = *(const float4*)(src + off + 4);
    uint4 o;
    o.x = (u32)f2b(f0.x) | ((u32)f2b(f0.y) << 16);
    o.y = (u32)f2b(f0.z) | ((u32)f2b(f0.w) << 16);
    o.z = (u32)f2b(f1.x) | ((u32)f2b(f1.y) << 16);
    o.w = (u32)f2b(f1.z) | ((u32)f2b(f1.w) << 16);
    *(uint4*)dst = o;
}

// ---------------------------------------------------------------------------
// Merged Q/K/V projection, pure-bf16 inputs, m97 structure.
// Grid (8,32,3) = 768 blocks = 3/CU exactly. LDS 32 KB.
// z==2 epilogue: transpose the 128x128 output tile in LDS (reusing the
// staging buffer, XOR-swizzled) => coalesced dwordx4 V^T stores.
// ---------------------------------------------------------------------------
__global__ __launch_bounds__(256, 3) void proj3_bf16(
    const u16* __restrict__ xb, const u16* __restrict__ wb,
    const float* __restrict__ bq, const float* __restrict__ bk, const float* __restrict__ bv,
    u16* __restrict__ qws, u16* __restrict__ kws, u16* __restrict__ vtws)
{
    __shared__ __align__(16) u16 smem[16384];   // 32 KB: la | lb, reused as 128x128 transpose buf
    u16 (*la)[4096] = reinterpret_cast<u16(*)[4096]>(smem);
    u16 (*lb)[4096] = reinterpret_cast<u16(*)[4096]>(smem + 8192);

    const int z = blockIdx.z;
    const u16* X = xb + ((size_t)z << 22);
    const u16* W = wb + ((size_t)z << 20);
    const float* Bi = (z == 0) ? bq : (z == 1) ? bk : bv;
    u16* dst       = (z == 0) ? qws : (z == 1) ? kws : vtws;

    const int tid  = threadIdx.x;
    const int wv_  = tid >> 6;
    const int lane = tid & 63;
    const int quad = lane >> 4;
    const int l15  = lane & 15;
    const int bx = blockIdx.y >> 2;                            // 0..7
    const int by = (blockIdx.x << 2) | (blockIdx.y & 3);       // 0..31
    const int wm = (wv_ >> 1) * 64;
    const int wn = (wv_ & 1) * 64;

    f32x4 acc[4][4];
    for (int i = 0; i < 4; ++i)
        for (int j = 0; j < 4; ++j)
            acc[i][j] = (f32x4){0.f, 0.f, 0.f, 0.f};

    const int rowA0 = by * 128;
    const int rowB0 = bx * 128;

    const int strow = tid >> 2;
    const int stcol = (tid & 3) * 8;
    const u16* gA0 = &X[(size_t)(rowA0 + strow) * D_MODEL + stcol];
    const u16* gA1 = gA0 + (size_t)64 * D_MODEL;
    const u16* gB0 = &W[(size_t)(rowB0 + strow) * D_MODEL + stcol];
    const u16* gB1 = gB0 + (size_t)64 * D_MODEL;
    const int l0 = tid * 8, l1 = 2048 + tid * 8;

    gload16(gA0, &la[0][l0]);
    gload16(gA1, &la[0][l1]);
    gload16(gB0, &lb[0][l0]);
    gload16(gB1, &lb[0][l1]);
    __syncthreads();

    for (int t = 0; t < 32; ++t) {
        const int buf = t & 1;
        if (t < 31) {
            const int ko = (t + 1) * 32;
            gload16(gA0 + ko, &la[buf ^ 1][l0]);
            gload16(gA1 + ko, &la[buf ^ 1][l1]);
            gload16(gB0 + ko, &lb[buf ^ 1][l0]);
            gload16(gB1 + ko, &lb[buf ^ 1][l1]);
        }
        bf16x8 af[4], bfr[4];
        #pragma unroll
        for (int tt = 0; tt < 4; ++tt) {
            af[tt]  = ldb8(&la[buf][(wm + tt * 16 + l15) * 32 + quad * 8]);
            bfr[tt] = ldb8(&lb[buf][(wn + tt * 16 + l15) * 32 + quad * 8]);
        }
        #pragma unroll
        for (int mt = 0; mt < 4; ++mt)
            #pragma unroll
            for (int nt = 0; nt < 4; ++nt)
                acc[mt][nt] = __builtin_amdgcn_mfma_f32_16x16x32_bf16(af[mt], bfr[nt], acc[mt][nt], 0, 0, 0);
        __syncthreads();
    }

    if (z != 2) {
        #pragma unroll
        for (int nt = 0; nt < 4; ++nt) {
            int n = rowB0 + wn + nt * 16 + l15;
            float bvv = Bi[n];
            int h = n >> 6, d = n & 63;
            #pragma unroll
            for (int mt = 0; mt < 4; ++mt) {
                #pragma unroll
                for (int r = 0; r < 4; ++r) {
                    int m = rowA0 + wm + mt * 16 + quad * 4 + r;
                    float c = acc[mt][nt][r] + bvv;
                    if (z == 0) c *= QSCALE;
                    int b = m >> 11, s = m & (SEQ - 1);
                    dst[(((size_t)(b * NHEADS + h) * SEQ) + s) * DEPTH + d] = f2b(c);
                }
            }
        }
    } else {
        // stage C^T (128 n x 128 m) into swizzled LDS, then coalesced stores.
        #pragma unroll
        for (int nt = 0; nt < 4; ++nt) {
            const int nl = wn + nt * 16 + l15;
            const float bvv = Bi[rowB0 + nl];
            #pragma unroll
            for (int mt = 0; mt < 4; ++mt) {
                #pragma unroll
                for (int r2 = 0; r2 < 4; r2 += 2) {
                    const int ml = wm + mt * 16 + quad * 4 + r2;   // even
                    u32 pk = (u32)f2b(acc[mt][nt][r2] + bvv)
                           | ((u32)f2b(acc[mt][nt][r2 + 1] + bvv) << 16);
                    const int g = ml >> 3;
                    *(u32*)&smem[nl * 128 + (((g ^ (nl & 15)) << 3) | (ml & 7))] = pk;
                }
            }
        }
        __syncthreads();
        const int nl  = tid >> 1;                 // local n row 0..127
        const int cc0 = (tid & 1) * 64;           // m half
        const int n   = rowB0 + nl;
        const int bb  = rowA0 >> 11;              // uniform per block
        u16* dbase = dst + (((size_t)(bb * NHEADS + (n >> 6)) * DEPTH) + (n & 63)) * SEQ
                   + (rowA0 & (SEQ - 1)) + cc0;
        #pragma unroll
        for (int j = 0; j < 8; ++j) {
            const int g = (tid & 1) * 8 + j;
            *(uint4*)&dbase[j * 8] =
                *(const uint4*)&smem[nl * 128 + ((g ^ (nl & 15)) << 3)];
        }
    }
}

// ---------------------------------------------------------------------------
// Fallback fused projection (fp32 in-kernel cvt) for small workspaces.
// ---------------------------------------------------------------------------
__global__ __launch_bounds__(256, 3) void proj3_fused(
    const float* __restrict__ q, const float* __restrict__ k, const float* __restrict__ v,
    const float* __restrict__ wq, const float* __restrict__ wk, const float* __restrict__ wv,
    const float* __restrict__ bq, const float* __restrict__ bk, const float* __restrict__ bv,
    u16* __restrict__ qws, u16* __restrict__ kws, u16* __restrict__ vtws)
{
    __shared__ __align__(16) u16 ldsA[128 * 40];
    __shared__ __align__(16) u16 ldsB[128 * 40];

    const int z = blockIdx.z;
    const float* X  = (z == 0) ? q  : (z == 1) ? k  : v;
    const float* W  = (z == 0) ? wq : (z == 1) ? wk : wv;
    const float* Bi = (z == 0) ? bq : (z == 1) ? bk : bv;
    u16* dst        = (z == 0) ? qws : (z == 1) ? kws : vtws;

    const int tid  = threadIdx.x;
    const int wv_  = tid >> 6;
    const int lane = tid & 63;
    const int quad = lane >> 4;
    const int l15  = lane & 15;
    const int bx = blockIdx.y >> 2;
    const int by = (blockIdx.x << 2) | (blockIdx.y & 3);
    const int wm = (wv_ >> 1) * 64;
    const int wn = (wv_ & 1) * 64;

    f32x4 acc[4][4];
    for (int i = 0; i < 4; ++i)
        for (int j = 0; j < 4; ++j)
            acc[i][j] = (f32x4){0.f, 0.f, 0.f, 0.f};

    const int rowA0 = by * 128;
    const int rowB0 = bx * 128;

    const int sr = tid >> 3;
    const int sc = (tid & 7) * 4;

    float4 pa[4], pb[4];
    #pragma unroll
    for (int i = 0; i < 4; ++i) {
        pa[i] = *(const float4*)&X[(size_t)(rowA0 + sr + i * 32) * D_MODEL + sc];
        pb[i] = *(const float4*)&W[(size_t)(rowB0 + sr + i * 32) * D_MODEL + sc];
    }

    for (int it = 0; it < 32; ++it) {
        #pragma unroll
        for (int i = 0; i < 4; ++i) {
            ushort4 ha, hb;
            ha.x = f2b(pa[i].x); ha.y = f2b(pa[i].y); ha.z = f2b(pa[i].z); ha.w = f2b(pa[i].w);
            hb.x = f2b(pb[i].x); hb.y = f2b(pb[i].y); hb.z = f2b(pb[i].z); hb.w = f2b(pb[i].w);
            *(ushort4*)&ldsA[(sr + i * 32) * 40 + sc] = ha;
            *(ushort4*)&ldsB[(sr + i * 32) * 40 + sc] = hb;
        }
        __syncthreads();

        if (it < 31) {
            const int k0 = (it + 1) * 32;
            #pragma unroll
            for (int i = 0; i < 4; ++i) {
                pa[i] = *(const float4*)&X[(size_t)(rowA0 + sr + i * 32) * D_MODEL + k0 + sc];
                pb[i] = *(const float4*)&W[(size_t)(rowB0 + sr + i * 32) * D_MODEL + k0 + sc];
            }
        }

        bf16x8 af[4], bfr[4];
        #pragma unroll
        for (int t = 0; t < 4; ++t) {
            af[t]  = ldb8(&ldsA[(wm + t * 16 + l15) * 40 + quad * 8]);
            bfr[t] = ldb8(&ldsB[(wn + t * 16 + l15) * 40 + quad * 8]);
        }
        #pragma unroll
        for (int mt = 0; mt < 4; ++mt)
            #pragma unroll
            for (int nt = 0; nt < 4; ++nt)
                acc[mt][nt] = __builtin_amdgcn_mfma_f32_16x16x32_bf16(af[mt], bfr[nt], acc[mt][nt], 0, 0, 0);
        __syncthreads();
    }

    #pragma unroll
    for (int nt = 0; nt < 4; ++nt) {
        int n = bx * 128 + wn + nt * 16 + l15;
        float bvv = Bi[n];
        int h = n >> 6, d = n & 63;
        #pragma unroll
        for (int mt = 0; mt < 4; ++mt) {
            #pragma unroll
            for (int r = 0; r < 4; ++r) {
                int m = by * 128 + wm + mt * 16 + quad * 4 + r;
                float c = acc[mt][nt][r] + bvv;
                if (z == 0) c *= QSCALE;
                int b = m >> 11, s = m & (SEQ - 1);
                if (z != 2)
                    dst[(((size_t)(b * NHEADS + h) * SEQ) + s) * DEPTH + d] = f2b(c);
                else
                    dst[(((size_t)(b * NHEADS + h) * DEPTH) + d) * SEQ + s] = f2b(c);
            }
        }
    }
}

// ---------------------------------------------------------------------------
// Output projection, pure-bf16, 64x64 tile. Grid (64,16) = 1024 blocks
// = 4 blocks/CU exact (LDS 16 KB) => 16 waves/CU, vs the old 128x64
// structure's 2 blocks/CU (latency-bound, ~30 us). Default linear-id
// mapping gives XCD locality: xcd = x%8; all 16 y-blocks of an A-panel
// share x => same XCD => A panel L2-resident.
// ---------------------------------------------------------------------------
__global__ __launch_bounds__(256, 4) void gemm_out_bf16(
    const u16* __restrict__ X, const u16* __restrict__ W,
    const float* __restrict__ bias, float* __restrict__ out)
{
    __shared__ __align__(16) u16 la[2][64 * 32];
    __shared__ __align__(16) u16 lb[2][64 * 32];

    const int tid  = threadIdx.x;
    const int wv_  = tid >> 6;
    const int lane = tid & 63;
    const int quad = lane >> 4;
    const int l15  = lane & 15;
    const int mx = blockIdx.x;                 // 0..63 (m-tile; x%8 = XCD)
    const int nx = blockIdx.y;                 // 0..15 (n-tile)
    const int wm = (wv_ >> 1) * 32;
    const int wn = (wv_ & 1) * 32;

    f32x4 acc[2][2];
    for (int i = 0; i < 2; ++i)
        for (int j = 0; j < 2; ++j)
            acc[i][j] = (f32x4){0.f, 0.f, 0.f, 0.f};

    const int rowA0 = mx * 64;
    const int rowB0 = nx * 64;

    const int strow = tid >> 2;                // 0..63
    const int stcol = (tid & 3) * 8;
    const u16* gA0 = &X[(size_t)(rowA0 + strow) * D_MODEL + stcol];
    const u16* gB0 = &W[(size_t)(rowB0 + strow) * D_MODEL + stcol];
    const int l0 = tid * 8;

    gload16(gA0, &la[0][l0]);
    gload16(gB0, &lb[0][l0]);
    __syncthreads();

    for (int t = 0; t < 32; ++t) {
        const int buf = t & 1;
        if (t < 31) {
            const int ko = (t + 1) * 32;
            gload16(gA0 + ko, &la[buf ^ 1][l0]);
            gload16(gB0 + ko, &lb[buf ^ 1][l0]);
        }
        bf16x8 af[2], bfr[2];
        #pragma unroll
        for (int tt = 0; tt < 2; ++tt) {
            af[tt]  = ldb8(&la[buf][(wm + tt * 16 + l15) * 32 + quad * 8]);
            bfr[tt] = ldb8(&lb[buf][(wn + tt * 16 + l15) * 32 + quad * 8]);
        }
        #pragma unroll
        for (int mt = 0; mt < 2; ++mt)
            #pragma unroll
            for (int nt = 0; nt < 2; ++nt)
                acc[mt][nt] = __builtin_amdgcn_mfma_f32_16x16x32_bf16(af[mt], bfr[nt], acc[mt][nt], 0, 0, 0);
        __syncthreads();
    }

    #pragma unroll
    for (int nt = 0; nt < 2; ++nt) {
        int n = rowB0 + wn + nt * 16 + l15;
        float bvv = bias[n];
        #pragma unroll
        for (int mt = 0; mt < 2; ++mt) {
            #pragma unroll
            for (int r = 0; r < 4; ++r) {
                int m = rowA0 + wm + mt * 16 + quad * 4 + r;
                out[(size_t)m * D_MODEL + n] = acc[mt][nt][r] + bvv;
            }
        }
    }
}

// ---------------------------------------------------------------------------
// Fallback output projection (fp32 W, reg-staged).
// ---------------------------------------------------------------------------
__global__ __launch_bounds__(256) void gemm_out_f32(
    const u16* __restrict__ X, const float* __restrict__ W,
    const float* __restrict__ bias, float* __restrict__ out)
{
    __shared__ __align__(16) u16 ldsA[128 * 40];
    __shared__ __align__(16) u16 ldsB[64 * 40];

    const int tid  = threadIdx.x;
    const int wv_  = tid >> 6;
    const int lane = tid & 63;
    const int quad = lane >> 4;
    const int l15  = lane & 15;
    const int bx = ((blockIdx.y >> 2) << 1) | (blockIdx.x >> 3);   // 0..15
    const int by = ((blockIdx.x & 7) << 2) | (blockIdx.y & 3);     // 0..31
    const int wm = (wv_ >> 1) * 64;
    const int wn = (wv_ & 1) * 32;

    f32x4 acc[4][2];
    for (int i = 0; i < 4; ++i)
        for (int j = 0; j < 2; ++j)
            acc[i][j] = (f32x4){0.f, 0.f, 0.f, 0.f};

    const int rowA0 = by * 128;
    const int rowB0 = bx * 64;

    const int ar = tid >> 2, akc = (tid & 3) * 8;
    const int br = tid >> 3, bc = (tid & 7) * 4;

    uint4  paA[2];
    float4 paB[2];
    #pragma unroll
    for (int i = 0; i < 2; ++i) {
        paA[i] = *(const uint4*)&X[(size_t)(rowA0 + ar + i * 64) * D_MODEL + akc];
        paB[i] = *(const float4*)&W[(size_t)(rowB0 + br + i * 32) * D_MODEL + bc];
    }

    for (int it = 0; it < 32; ++it) {
        #pragma unroll
        for (int i = 0; i < 2; ++i) {
            *(uint4*)&ldsA[(ar + i * 64) * 40 + akc] = paA[i];
            ushort4 hb;
            hb.x = f2b(paB[i].x); hb.y = f2b(paB[i].y); hb.z = f2b(paB[i].z); hb.w = f2b(paB[i].w);
            *(ushort4*)&ldsB[(br + i * 32) * 40 + bc] = hb;
        }
        __syncthreads();

        if (it < 31) {
            const int k0 = (it + 1) * 32;
            #pragma unroll
            for (int i = 0; i < 2; ++i) {
                paA[i] = *(const uint4*)&X[(size_t)(rowA0 + ar + i * 64) * D_MODEL + k0 + akc];
                paB[i] = *(const float4*)&W[(size_t)(rowB0 + br + i * 32) * D_MODEL + k0 + bc];
            }
        }

        bf16x8 af[4], bfr[2];
        #pragma unroll
        for (int t = 0; t < 4; ++t)
            af[t] = ldb8(&ldsA[(wm + t * 16 + l15) * 40 + quad * 8]);
        #pragma unroll
        for (int t = 0; t < 2; ++t)
            bfr[t] = ldb8(&ldsB[(wn + t * 16 + l15) * 40 + quad * 8]);
        #pragma unroll
        for (int mt = 0; mt < 4; ++mt)
            #pragma unroll
            for (int nt = 0; nt < 2; ++nt)
                acc[mt][nt] = __builtin_amdgcn_mfma_f32_16x16x32_bf16(af[mt], bfr[nt], acc[mt][nt], 0, 0, 0);
        __syncthreads();
    }

    #pragma unroll
    for (int nt = 0; nt < 2; ++nt) {
        int n = bx * 64 + wn + nt * 16 + l15;
        float bvv = bias[n];
        #pragma unroll
        for (int mt = 0; mt < 4; ++mt) {
            #pragma unroll
            for (int r = 0; r < 4; ++r) {
                int m = by * 128 + wm + mt * 16 + quad * 4 + r;
                out[(size_t)m * D_MODEL + n] = acc[mt][nt][r] + bvv;
            }
        }
    }
}

// ---------------------------------------------------------------------------
// Flash attention (FROZEN: proven 70.2 us). QBLK=16/wave, K/V double-buffered
// via global_load_lds (linear dest, inverse-swizzled source), swapped QK^T,
// LDS 40960 => 4 blk/CU, grid (32,32) = 1024 = 4*256 zero tail.
// ---------------------------------------------------------------------------
__global__ __launch_bounds__(256, 4) void flash_attn(
    const u16* __restrict__ Q, const u16* __restrict__ K,
    const u16* __restrict__ Vt, const u64* __restrict__ maskbits,
    u16* __restrict__ O)
{
    __shared__ __align__(16) u16 ldsK[2][64 * 64];
    __shared__ __align__(16) u16 ldsV[2][64 * 64];
    __shared__ __align__(16) u16 ldsP[4][16 * 64];

    const int tid  = threadIdx.x;
    const int wv_  = tid >> 6;
    const int lane = tid & 63;
    const int quad = lane >> 4;
    const int l15  = lane & 15;
    const int bh = ((blockIdx.x & 7) << 2) | (blockIdx.y & 3);     // 0..31
    const int qt = ((blockIdx.y >> 2) << 2) | (blockIdx.x >> 3);   // 0..31
    const int b  = bh >> 4, h = bh & 15;
    const int q0 = qt * 64 + wv_ * 16;

    const u16* Qb = Q  + (size_t)bh * SEQ * DEPTH;
    const u16* Kb = K  + (size_t)bh * SEQ * DEPTH;
    const u16* Vb = Vt + (size_t)bh * DEPTH * SEQ;
    const u64* MB = maskbits + (size_t)b * SEQ * (SEQ / 64);

    const int sr8  = tid >> 3;                 // 0..31
    const int sg   = tid & 7;
    const int scol = ((sg ^ (sr8 & 7)) * 8);   // (sr8+32)&7 == sr8&7
    const u16* kS0 = &Kb[(size_t)sr8 * DEPTH + scol];
    const u16* kS1 = &Kb[(size_t)(sr8 + 32) * DEPTH + scol];
    const u16* vS0 = &Vb[(size_t)sr8 * SEQ + scol];
    const u16* vS1 = &Vb[(size_t)(sr8 + 32) * SEQ + scol];
    const int ld0 = tid * 8, ld1 = 2048 + tid * 8;

    const int xk0 = ((quad ^ (l15 & 7)) * 8);
    const int xk1 = (((4 + quad) ^ (l15 & 7)) * 8);

    bf16x8 aq0 = ldb8(&Qb[(q0 + l15) * DEPTH + quad * 8]);
    bf16x8 aq1 = ldb8(&Qb[(q0 + l15) * DEPTH + 32 + quad * 8]);

    bf16x8 vones;
    #pragma unroll
    for (int i = 0; i < 8; ++i) vones[i] = (__bf16)1.0f;

    f32x4 oa[4];
    for (int i = 0; i < 4; ++i) oa[i] = (f32x4){0.f, 0.f, 0.f, 0.f};
    f32x4 lacc = (f32x4){0.f, 0.f, 0.f, 0.f};

    u16* myP = ldsP[wv_];

    int wpq[4];
    #pragma unroll
    for (int cc = 0; cc < 4; ++cc) {
        const int g = cc * 2 + (quad >> 1);
        wpq[cc] = l15 * 64 + ((g ^ (l15 & 7)) * 8) + (quad & 1) * 4;
    }
    const int rp0 = l15 * 64 + ((quad ^ (l15 & 7)) * 8);
    const int rp1 = l15 * 64 + (((4 + quad) ^ (l15 & 7)) * 8);

    gload16(kS0, &ldsK[0][ld0]);
    gload16(kS1, &ldsK[0][ld1]);
    gload16(vS0, &ldsV[0][ld0]);
    gload16(vS1, &ldsV[0][ld1]);
    __syncthreads();

    for (int it = 0; it < 32; ++it) {
        const int buf = it & 1;
        const u16* Kl = ldsK[buf];
        const u16* Vl = ldsV[buf];

        if (it < 31) {
            const int kb2 = (it + 1) * 64;
            gload16(kS0 + (size_t)kb2 * DEPTH, &ldsK[buf ^ 1][ld0]);
            gload16(kS1 + (size_t)kb2 * DEPTH, &ldsK[buf ^ 1][ld1]);
            gload16(vS0 + kb2, &ldsV[buf ^ 1][ld0]);
            gload16(vS1 + kb2, &ldsV[buf ^ 1][ld1]);
        }

        const u64 t = MB[(size_t)(q0 + l15) * (SEQ / 64) + it];
        const u32 tlo = (u32)t, thi = (u32)(t >> 32);

        #pragma unroll
        for (int cc = 0; cc < 4; ++cc) {
            const int row = cc * 16 + l15;
            bf16x8 bk0 = ldb8(&Kl[row * 64 + xk0]);
            bf16x8 bk1 = ldb8(&Kl[row * 64 + xk1]);
            f32x4 z = (f32x4){0.f, 0.f, 0.f, 0.f};
            z = __builtin_amdgcn_mfma_f32_16x16x32_bf16(bk0, aq0, z, 0, 0, 0);
            z = __builtin_amdgcn_mfma_f32_16x16x32_bf16(bk1, aq1, z, 0, 0, 0);
            const u32 w = (cc & 2) ? thi : tlo;
            float p[4];
            #pragma unroll
            for (int r = 0; r < 4; ++r) {
                const u32 bit = (w >> ((cc & 1) * 16 + quad * 4 + r)) & 1u;
                float e = EXP2(z[r]);            // Q pre-scaled by 0.125*log2(e)
                p[r] = bit ? 0.f : e;
            }
            uint2 pk;
            pk.x = (u32)f2b(p[0]) | ((u32)f2b(p[1]) << 16);
            pk.y = (u32)f2b(p[2]) | ((u32)f2b(p[3]) << 16);
            *(uint2*)&myP[wpq[cc]] = pk;
        }

        __builtin_amdgcn_wave_barrier();
        __builtin_amdgcn_s_waitcnt(0xc07f);   // lgkmcnt(0)
        __builtin_amdgcn_wave_barrier();
        bf16x8 pa0 = ldb8(&myP[rp0]);
        bf16x8 pa1 = ldb8(&myP[rp1]);

        lacc = __builtin_amdgcn_mfma_f32_16x16x32_bf16(pa0, vones, lacc, 0, 0, 0);
        lacc = __builtin_amdgcn_mfma_f32_16x16x32_bf16(pa1, vones, lacc, 0, 0, 0);

        #pragma unroll
        for (int n = 0; n < 4; ++n) {
            const int row = n * 16 + l15;
            bf16x8 bv0 = ldb8(&Vl[row * 64 + xk0]);
            bf16x8 bv1 = ldb8(&Vl[row * 64 + xk1]);
            oa[n] = __builtin_amdgcn_mfma_f32_16x16x32_bf16(pa0, bv0, oa[n], 0, 0, 0);
            oa[n] = __builtin_amdgcn_mfma_f32_16x16x32_bf16(pa1, bv1, oa[n], 0, 0, 0);
        }

        __syncthreads();   // drains vmcnt: next tile staged; this tile's reads done
    }

    float inv[4];
    #pragma unroll
    for (int r = 0; r < 4; ++r)
        inv[r] = 1.0f / lacc[r];

    #pragma unroll
    for (int n = 0; n < 4; ++n)
        #pragma unroll
        for (int r = 0; r < 4; ++r) {
            int m = q0 + quad * 4 + r;
            O[((size_t)b * SEQ + m) * D_MODEL + h * DEPTH + n * 16 + l15] =
                f2b(oa[n][r] * inv[r]);
        }
}

// ---------------------------------------------------------------------------
extern "C" void kernel_launch(void* const* d_in, const int* in_sizes, int n_in,
                              void* d_out, int out_size, void* d_ws, size_t ws_size,
                              hipStream_t stream) {
    const float* q    = (const float*)d_in[0];
    const float* k    = (const float*)d_in[1];
    const float* v    = (const float*)d_in[2];
    const float* mask = (const float*)d_in[3];
    const float* wq   = (const float*)d_in[4];
    const float* bq   = (const float*)d_in[5];
    const float* wk   = (const float*)d_in[6];
    const float* bk   = (const float*)d_in[7];
    const float* wv   = (const float*)d_in[8];
    const float* bv   = (const float*)d_in[9];
    const float* wo   = (const float*)d_in[10];
    const float* bo   = (const float*)d_in[11];

    // ws (u16 units): [qws 4M][kws 4M][vtws 4M][ows 4M][mbits 512K][wb 4M][xb 12M]
    u16* base = (u16*)d_ws;
    const size_t seg = (size_t)BATCH * NHEADS * SEQ * DEPTH;  // 4M elems
    u16* qws  = base;
    u16* kws  = base + seg;
    u16* vtws = base + 2 * seg;
    u16* ows  = base + 3 * seg;
    u64* mbits = (u64*)(base + 4 * seg);
    u16* wb   = base + 4 * seg + 524288;
    u16* xb   = wb + 4 * 1048576;
    const size_t need_bf16 = (4 * seg + 524288 + 4 * 1048576 + 3 * seg) * 2;
    const bool bf16path = (ws_size >= need_bf16);

    dim3 blk(256);
    dim3 gp(D_MODEL / 128, MROWS / 128, 3);   // (8, 32, 3)
    if (bf16path) {
        // fused cvt + mask pack: 8192 cvt blocks + 32768 pack blocks
        hipLaunchKernelGGL(cvt_pack, dim3(8192 + 32768), blk, 0, stream,
                           q, k, v, wq, wk, wv, wo, mask, xb, wb, mbits);
        hipLaunchKernelGGL(proj3_bf16, gp, blk, 0, stream,
                           xb, wb, bq, bk, bv, qws, kws, vtws);
    } else {
        hipLaunchKernelGGL(pack_mask, dim3(BATCH * SEQ * (SEQ / 64) / 4), blk, 0, stream, mask, mbits);
        hipLaunchKernelGGL(proj3_fused, gp, blk, 0, stream,
                           q, k, v, wq, wk, wv, bq, bk, bv, qws, kws, vtws);
    }

    dim3 ga(32, 32);                          // 1024 blocks = 4/CU
    hipLaunchKernelGGL(flash_attn, ga, blk, 0, stream, qws, kws, vtws, mbits, ows);

    if (bf16path) {
        dim3 go(MROWS / 64, D_MODEL / 64);    // (64, 16) = 1024 blocks = 4/CU
        hipLaunchKernelGGL(gemm_out_bf16, go, blk, 0, stream, ows, wb + 3 * 1048576, bo, (float*)d_out);
    } else {
        dim3 go(D_MODEL / 64, MROWS / 128);   // (16, 32)
        hipLaunchKernelGGL(gemm_out_f32, go, blk, 0, stream, ows, wo, bo, (float*)d_out);
    }
}